// Round 3
// baseline (5920.929 us; speedup 1.0000x reference)
//
#include <hip/hip_runtime.h>
#include <hip/hip_bf16.h>
#include <math.h>

#define N_NODES 4096
#define WPN 32
#define HID 1024
#define VOCAB 30000
#define NCLASS 4
#define NLEAVES 1024

typedef unsigned int u32;
typedef unsigned short u16;

__device__ __forceinline__ float sigmf(float x){ return 1.f/(1.f+expf(-x)); }

// ---------------------------------------------------------------------------
// Level schedule: depth[i] via iterative relaxation in LDS, then counting sort.
// Also zeroes node_h row 0 (root parent).
// ---------------------------------------------------------------------------
__global__ __launch_bounds__(1024) void k_levels(const int* __restrict__ parent,
                                                 int* __restrict__ meta,
                                                 int* __restrict__ lstart,
                                                 int* __restrict__ order,
                                                 float* __restrict__ node_h){
  __shared__ int dep[N_NODES];
  __shared__ int dpt[N_NODES];
  __shared__ int cnt[N_NODES];
  __shared__ int changed, maxd;
  const int t = threadIdx.x;
  for(int i=t;i<N_NODES;i+=1024){ dep[i]=parent[i]-1; dpt[i]=0; cnt[i]=0; }
  if(t==0){ maxd=0; }
  node_h[t]=0.f;  // 1024 threads == HID: zero root-parent row
  __syncthreads();
  while(true){
    if(t==0) changed=0;
    __syncthreads();
    bool ch=false;
    for(int i=t;i<N_NODES;i+=1024){
      int d = (dep[i]<0)? 0 : (dpt[dep[i]]+1);
      if(d>dpt[i]){ dpt[i]=d; ch=true; }
    }
    if(ch) changed=1;
    __syncthreads();
    if(!changed) break;
    __syncthreads();
  }
  __syncthreads();
  for(int i=t;i<N_NODES;i+=1024){ atomicAdd(&cnt[dpt[i]],1); atomicMax(&maxd,dpt[i]); }
  __syncthreads();
  // inclusive scan of cnt -> sc (reuse dep)
  int* sc = dep;
  for(int i=t;i<N_NODES;i+=1024) sc[i]=cnt[i];
  __syncthreads();
  for(int off=1; off<N_NODES; off<<=1){
    int v[4];
    #pragma unroll
    for(int u=0;u<4;u++){ int i=t+u*1024; v[u] = (i>=off)? sc[i-off] : 0; }
    __syncthreads();
    #pragma unroll
    for(int u=0;u<4;u++){ int i=t+u*1024; sc[i]+=v[u]; }
    __syncthreads();
  }
  for(int i=t;i<N_NODES;i+=1024) lstart[i+1]=sc[i];
  if(t==0){ lstart[0]=0; meta[0]=maxd+1; }
  // exclusive starts into cnt for scatter
  for(int i=t;i<N_NODES;i+=1024) cnt[i]=sc[i]-cnt[i];
  __syncthreads();
  for(int i=t;i<N_NODES;i+=1024){
    int pos = atomicAdd(&cnt[dpt[i]],1);
    order[pos]=i;
  }
}

// ---------------------------------------------------------------------------
// E [HID][VOCAB] f32  ->  ET [VOCAB][HID] f32  (tiled transpose)
// ---------------------------------------------------------------------------
__global__ __launch_bounds__(256) void k_transpose(const float* __restrict__ E,
                                                   float* __restrict__ ET){
  __shared__ float tile[32][33];
  const int v0 = blockIdx.x*32, h0 = blockIdx.y*32;
  const int tx = threadIdx.x%32, ty = threadIdx.x/32;   // ty 0..7
  #pragma unroll
  for(int i=0;i<4;i++){
    int h = h0+ty+8*i, v = v0+tx;
    tile[ty+8*i][tx] = (v<VOCAB)? E[(size_t)h*VOCAB + v] : 0.f;
  }
  __syncthreads();
  #pragma unroll
  for(int i=0;i<4;i++){
    int v = v0+ty+8*i, h = h0+tx;
    if(v<VOCAB) ET[(size_t)v*HID + h] = tile[tx][ty+8*i];
  }
}

// ---------------------------------------------------------------------------
// xe[n,h] = sum_l w[n,l] * ET[idx[n,l], h]   (one block per node, coalesced)
// ---------------------------------------------------------------------------
__global__ __launch_bounds__(256) void k_xe(const float* __restrict__ ET,
                                            const float* __restrict__ xw,
                                            const int* __restrict__ xi,
                                            float* __restrict__ xe){
  const int n = blockIdx.x;
  __shared__ float w[WPN]; __shared__ int id[WPN];
  const int t = threadIdx.x;
  if(t<WPN){ w[t]=xw[n*WPN+t]; id[t]=xi[n*WPN+t]; }
  __syncthreads();
  const int h0 = t*4;
  float a0=0,a1=0,a2=0,a3=0;
  for(int l=0;l<WPN;l++){
    const float4 e = *(const float4*)(ET + (size_t)id[l]*HID + h0);
    const float wl = w[l];
    a0 += wl*e.x; a1 += wl*e.y; a2 += wl*e.z; a3 += wl*e.w;
  }
  *(float4*)(xe + (size_t)n*HID + h0) = make_float4(a0,a1,a2,a3);
}

// Fallback when ws too small for fp32 ET: direct strided gather from E.
// E (123MB) fits in the 256MB Infinity Cache, so re-reads are L3-served.
__global__ __launch_bounds__(256) void k_xe_noET(const float* __restrict__ E,
                                                 const float* __restrict__ xw,
                                                 const int* __restrict__ xi,
                                                 float* __restrict__ xe){
  const int n = blockIdx.x;
  __shared__ float w[WPN]; __shared__ int id[WPN];
  const int t = threadIdx.x;
  if(t<WPN){ w[t]=xw[n*WPN+t]; id[t]=xi[n*WPN+t]; }
  __syncthreads();
  const int h0 = t*4;
  float acc[4]={0,0,0,0};
  for(int l=0;l<WPN;l++){
    const float wl=w[l]; const int ix=id[l];
    #pragma unroll
    for(int j=0;j<4;j++) acc[j] += wl*E[(size_t)(h0+j)*VOCAB + ix];
  }
  *(float4*)(xe + (size_t)n*HID + h0) = make_float4(acc[0],acc[1],acc[2],acc[3]);
}

// ---------------------------------------------------------------------------
// Input-side projections: out_g[n,o] = b_g[o] + sum_k xe[n,k]*W_g[o,k]
// 64x64 tile, BK=32, k-major LDS, 4x4 micro-tile.
// ---------------------------------------------------------------------------
__global__ __launch_bounds__(256) void k_gemm_in(const float* __restrict__ xe,
  const float* __restrict__ W0,const float* __restrict__ W1,const float* __restrict__ W2,
  const float* __restrict__ b0,const float* __restrict__ b1,const float* __restrict__ b2,
  float* __restrict__ o0p,float* __restrict__ o1p,float* __restrict__ o2p){
  __shared__ float A[32*68];
  __shared__ float B[32*68];
  const int g=blockIdx.z;
  const float* W  = (g==0)?W0:((g==1)?W1:W2);
  const float* bi = (g==0)?b0:((g==1)?b1:b2);
  float* out      = (g==0)?o0p:((g==1)?o1p:o2p);
  const int n0=blockIdx.x<<6, q0=blockIdx.y<<6;
  const int t=threadIdx.x, tx=t&15, ty=t>>4;
  float acc[4][4]={};
  for(int k0=0;k0<HID;k0+=32){
    #pragma unroll
    for(int m=0;m<2;m++){
      int idx=t+(m<<8); int r=idx>>3; int c4=(idx&7)<<2;
      float4 v=*(const float4*)(xe+(size_t)(n0+r)*HID+k0+c4);
      A[(c4+0)*68+r]=v.x; A[(c4+1)*68+r]=v.y; A[(c4+2)*68+r]=v.z; A[(c4+3)*68+r]=v.w;
      float4 u=*(const float4*)(W+(size_t)(q0+r)*HID+k0+c4);
      B[(c4+0)*68+r]=u.x; B[(c4+1)*68+r]=u.y; B[(c4+2)*68+r]=u.z; B[(c4+3)*68+r]=u.w;
    }
    __syncthreads();
    #pragma unroll 8
    for(int k=0;k<32;k++){
      const float4 a=*(const float4*)&A[k*68+(ty<<2)];
      const float4 b=*(const float4*)&B[k*68+(tx<<2)];
      acc[0][0]+=a.x*b.x; acc[0][1]+=a.x*b.y; acc[0][2]+=a.x*b.z; acc[0][3]+=a.x*b.w;
      acc[1][0]+=a.y*b.x; acc[1][1]+=a.y*b.y; acc[1][2]+=a.y*b.z; acc[1][3]+=a.y*b.w;
      acc[2][0]+=a.z*b.x; acc[2][1]+=a.z*b.y; acc[2][2]+=a.z*b.z; acc[2][3]+=a.z*b.w;
      acc[3][0]+=a.w*b.x; acc[3][1]+=a.w*b.y; acc[3][2]+=a.w*b.z; acc[3][3]+=a.w*b.w;
    }
    __syncthreads();
  }
  const float4 bb=*(const float4*)(bi+q0+(tx<<2));
  #pragma unroll
  for(int i=0;i<4;i++){
    const int n=n0+(ty<<2)+i;
    float4 r4 = make_float4(acc[i][0]+bb.x, acc[i][1]+bb.y, acc[i][2]+bb.z, acc[i][3]+bb.w);
    *(float4*)(out+(size_t)n*HID+q0+(tx<<2)) = r4;
  }
}

// ---------------------------------------------------------------------------
// Persistent level-synchronous recurrence kernel (grid barrier via atomics).
// ---------------------------------------------------------------------------
__device__ __forceinline__ void gbar(u32* bar, u32 nb){
  __syncthreads();
  if(threadIdx.x==0){
    __threadfence();
    u32* cnt = bar;
    u32* gen = bar+32;   // separate cacheline
    u32 g = __hip_atomic_load(gen, __ATOMIC_RELAXED, __HIP_MEMORY_SCOPE_AGENT);
    u32 a = __hip_atomic_fetch_add(cnt, 1u, __ATOMIC_ACQ_REL, __HIP_MEMORY_SCOPE_AGENT);
    if(a == nb-1u){
      __hip_atomic_store(cnt, 0u, __ATOMIC_RELAXED, __HIP_MEMORY_SCOPE_AGENT);
      __hip_atomic_fetch_add(gen, 1u, __ATOMIC_RELEASE, __HIP_MEMORY_SCOPE_AGENT);
    }else{
      while(__hip_atomic_load(gen, __ATOMIC_ACQUIRE, __HIP_MEMORY_SCOPE_AGENT)==g){
        __builtin_amdgcn_s_sleep(2);
      }
    }
    __threadfence();
  }
  __syncthreads();
}

__global__ __launch_bounds__(256,1) void k_rec(
    const int* __restrict__ parent,
    const float* __restrict__ Uz, const float* __restrict__ Ur, const float* __restrict__ Uh,
    float* __restrict__ wz, float* __restrict__ wr, float* __restrict__ wh,
    float* __restrict__ node_h,
    const int* __restrict__ meta, const int* __restrict__ lstart, const int* __restrict__ order,
    u32* __restrict__ bar){
  __shared__ float A[32*68];   // U tile, k-major [k][row]
  __shared__ float B[32*36];   // PH tile, k-major [k][col]
  __shared__ int nds[32], prw[32];
  const int t=threadIdx.x, tx=t&15, ty=t>>4;
  const u32 nb = gridDim.x;
  const int nlev = meta[0];

  // mode 0: z-gate (wz = sigmoid(wz + Uz@ph))       B rows = node_h[parent]
  // mode 1: r-gate (r=sigmoid(wr+Ur@ph); wr = ph*r)
  // mode 2: h:      c=tanh(wh+Uh@(ph*r)); node_h[n+1]=z*ph+(1-z)*c   B rows = wr[n]
  auto task_body = [&](const float* __restrict__ U, const float* __restrict__ Bsrc,
                       const int* __restrict__ bIdx, int mode, int Lj, int ro){
    float acc[4][2]={};
    for(int k0=0;k0<HID;k0+=32){
      #pragma unroll
      for(int m=0;m<2;m++){
        int idx=t+(m<<8); int r=idx>>3; int c4=(idx&7)<<2;
        const float4 v = *(const float4*)(U + (size_t)(ro+r)*HID + k0+c4);
        A[(c4+0)*68+r]=v.x; A[(c4+1)*68+r]=v.y; A[(c4+2)*68+r]=v.z; A[(c4+3)*68+r]=v.w;
      }
      {
        int j=t>>3; int c4=(t&7)<<2;
        if(j<Lj){
          const float4 v = *(const float4*)(Bsrc + (size_t)bIdx[j]*HID + k0+c4);
          B[(c4+0)*36+j]=v.x; B[(c4+1)*36+j]=v.y; B[(c4+2)*36+j]=v.z; B[(c4+3)*36+j]=v.w;
        }
      }
      __syncthreads();
      #pragma unroll 8
      for(int k=0;k<32;k++){
        const float4 a = *(const float4*)&A[k*68+(ty<<2)];
        const float2 b = *(const float2*)&B[k*36+(tx<<1)];
        acc[0][0]+=a.x*b.x; acc[0][1]+=a.x*b.y;
        acc[1][0]+=a.y*b.x; acc[1][1]+=a.y*b.y;
        acc[2][0]+=a.z*b.x; acc[2][1]+=a.z*b.y;
        acc[3][0]+=a.w*b.x; acc[3][1]+=a.w*b.y;
      }
      __syncthreads();
    }
    const int o0 = ro + (ty<<2);
    #pragma unroll
    for(int c=0;c<2;c++){
      const int jl=(tx<<1)+c;
      if(jl<Lj){
        const int n = nds[jl];
        if(mode==0){
          float* dst = wz + (size_t)n*HID + o0;
          float4 w4 = *(float4*)dst;
          w4.x=sigmf(w4.x+acc[0][c]); w4.y=sigmf(w4.y+acc[1][c]);
          w4.z=sigmf(w4.z+acc[2][c]); w4.w=sigmf(w4.w+acc[3][c]);
          *(float4*)dst = w4;
        }else if(mode==1){
          float* dst = wr + (size_t)n*HID + o0;
          float4 w4 = *(float4*)dst;
          const float4 ph = *(const float4*)(node_h + (size_t)prw[jl]*HID + o0);
          w4.x=sigmf(w4.x+acc[0][c])*ph.x; w4.y=sigmf(w4.y+acc[1][c])*ph.y;
          w4.z=sigmf(w4.z+acc[2][c])*ph.z; w4.w=sigmf(w4.w+acc[3][c])*ph.w;
          *(float4*)dst = w4;
        }else{
          const float4 w4 = *(const float4*)(wh + (size_t)n*HID + o0);
          const float4 z4 = *(const float4*)(wz + (size_t)n*HID + o0);
          const float4 ph = *(const float4*)(node_h + (size_t)prw[jl]*HID + o0);
          float4 hn;
          hn.x = z4.x*ph.x + (1.f-z4.x)*tanhf(w4.x+acc[0][c]);
          hn.y = z4.y*ph.y + (1.f-z4.y)*tanhf(w4.y+acc[1][c]);
          hn.z = z4.z*ph.z + (1.f-z4.z)*tanhf(w4.z+acc[2][c]);
          hn.w = z4.w*ph.w + (1.f-z4.w)*tanhf(w4.w+acc[3][c]);
          *(float4*)(node_h + (size_t)(n+1)*HID + o0) = hn;
        }
      }
    }
    __syncthreads();
  };

  for(int lev=0; lev<nlev; ++lev){
    const int s=lstart[lev], e=lstart[lev+1];
    const int L=e-s;
    const int jc=(L+31)>>5;
    const int tA = jc<<5;          // 2 gates * 16 rowchunks * jc
    for(int task=blockIdx.x; task<tA; task+=nb){
      const int jci = task % jc;
      const int rest= task / jc;
      const int rc  = rest & 15;
      const int gate= rest >> 4;
      const int j0  = jci<<5;
      const int Lj  = min(32, L-j0);
      if(t<32){
        int n = (t<Lj)? order[s+j0+t] : 0;
        nds[t]=n; prw[t]=parent[n];
      }
      __syncthreads();
      task_body(gate?Ur:Uz, node_h, prw, gate?1:0, Lj, rc<<6);
    }
    gbar(bar, nb);
    const int tC = jc<<4;          // 16 rowchunks * jc
    for(int task=blockIdx.x; task<tC; task+=nb){
      const int jci = task % jc;
      const int rc  = (task/jc) & 15;
      const int j0  = jci<<5;
      const int Lj  = min(32, L-j0);
      if(t<32){
        int n = (t<Lj)? order[s+j0+t] : 0;
        nds[t]=n; prw[t]=parent[n];
      }
      __syncthreads();
      task_body(Uh, wr, nds, 2, Lj, rc<<6);
    }
    gbar(bar, nb);
  }
}

// ---------------------------------------------------------------------------
// Leaf max + softmax + loss. Output: FP32 pred[4], loss  (reference output
// dtype is float32 — round-1/2 failure was writing bf16 here).
// ---------------------------------------------------------------------------
__global__ __launch_bounds__(1024) void k_final(const float* __restrict__ node_h,
                                                const int* __restrict__ leaf,
                                                const float* __restrict__ Wout,
                                                const float* __restrict__ bout,
                                                const float* __restrict__ y,
                                                float* __restrict__ out){
  __shared__ int li[NLEAVES];
  __shared__ float fs[HID];
  __shared__ float logits[NCLASS];
  const int t=threadIdx.x;
  li[t]=leaf[t];
  __syncthreads();
  float m=-INFINITY;
  for(int l=0;l<NLEAVES;l++) m = fmaxf(m, node_h[(size_t)li[l]*HID + t]);
  fs[t]=m;
  __syncthreads();
  const int wave=t>>6, lane=t&63;
  if(wave<NCLASS){
    float p=0.f;
    for(int h=lane;h<HID;h+=64) p += Wout[wave*HID+h]*fs[h];
    for(int off=32; off; off>>=1) p += __shfl_down(p, off);
    if(lane==0) logits[wave]=p+bout[wave];
  }
  __syncthreads();
  if(t==0){
    float mx = fmaxf(fmaxf(logits[0],logits[1]),fmaxf(logits[2],logits[3]));
    float ev[NCLASS]; float es=0.f;
    #pragma unroll
    for(int c=0;c<NCLASS;c++){ ev[c]=expf(logits[c]-mx); es+=ev[c]; }
    float loss=0.f;
    #pragma unroll
    for(int c=0;c<NCLASS;c++){
      float p=ev[c]/es;
      out[c]=p;
      float d=y[c]-p; loss+=d*d;
    }
    out[NCLASS]=loss;
  }
}

// ---------------------------------------------------------------------------
extern "C" void kernel_launch(void* const* d_in, const int* in_sizes, int n_in,
                              void* d_out, int out_size, void* d_ws, size_t ws_size,
                              hipStream_t stream){
  (void)in_sizes; (void)n_in; (void)out_size;
  const float* x_word=(const float*)d_in[0];
  const int*   x_index=(const int*)d_in[1];
  const int*   parent =(const int*)d_in[2];
  const int*   leaf   =(const int*)d_in[3];
  const float* y      =(const float*)d_in[4];
  const float* E      =(const float*)d_in[5];
  const float* W_z=(const float*)d_in[6];  const float* U_z=(const float*)d_in[7];  const float* b_z=(const float*)d_in[8];
  const float* W_r=(const float*)d_in[9];  const float* U_r=(const float*)d_in[10]; const float* b_r=(const float*)d_in[11];
  const float* W_h=(const float*)d_in[12]; const float* U_h=(const float*)d_in[13]; const float* b_h=(const float*)d_in[14];
  const float* W_out=(const float*)d_in[15]; const float* b_out=(const float*)d_in[16];

  size_t off=0;
  char* wsb=(char*)d_ws;
  auto alloc=[&](size_t b)->void*{ void* p=wsb+off; off=(off+b+255)&~(size_t)255; return p; };
  u32*  bar    = (u32*)  alloc(256);
  int*  meta   = (int*)  alloc(256);
  int*  lstart = (int*)  alloc((N_NODES+1)*sizeof(int));
  int*  order  = (int*)  alloc(N_NODES*sizeof(int));
  float* node_h= (float*)alloc((size_t)(N_NODES+1)*HID*sizeof(float));
  float* xe    = (float*)alloc((size_t)N_NODES*HID*sizeof(float));
  float* wz    = (float*)alloc((size_t)N_NODES*HID*sizeof(float));
  float* wr    = (float*)alloc((size_t)N_NODES*HID*sizeof(float));
  float* wh    = (float*)alloc((size_t)N_NODES*HID*sizeof(float));
  float* ET    = (float*)(wsb+off);
  const size_t need_ET = off + (size_t)VOCAB*HID*sizeof(float);
  const bool useET = (ws_size >= need_ET);

  hipMemsetAsync(bar, 0, 256, stream);
  k_levels<<<1,1024,0,stream>>>(parent, meta, lstart, order, node_h);
  if(useET){
    k_transpose<<<dim3((VOCAB+31)/32, HID/32),256,0,stream>>>(E, ET);
    k_xe<<<N_NODES,256,0,stream>>>(ET, x_word, x_index, xe);
  }else{
    k_xe_noET<<<N_NODES,256,0,stream>>>(E, x_word, x_index, xe);
  }
  k_gemm_in<<<dim3(N_NODES/64, HID/64, 3),256,0,stream>>>(xe, W_z,W_r,W_h, b_z,b_r,b_h, wz,wr,wh);
  k_rec<<<256,256,0,stream>>>(parent, U_z,U_r,U_h, wz,wr,wh, node_h, meta, lstart, order, bar);
  k_final<<<1,1024,0,stream>>>(node_h, leaf, W_out, b_out, y, (float*)d_out);
}

// Round 4
// 5852.044 us; speedup vs baseline: 1.0118x; 1.0118x over previous
//
#include <hip/hip_runtime.h>
#include <hip/hip_bf16.h>
#include <math.h>

#define N_NODES 4096
#define WPN 32
#define HID 1024
#define VOCAB 30000
#define NCLASS 4
#define NLEAVES 1024

typedef unsigned int u32;
typedef unsigned short u16;

__device__ __forceinline__ float sigmf(float x){ return 1.f/(1.f+expf(-x)); }

// ---------------------------------------------------------------------------
// Level schedule: depth[i] via iterative relaxation in LDS, then counting sort.
// Also zeroes node_h row 0 (root parent).
// ---------------------------------------------------------------------------
__global__ __launch_bounds__(1024) void k_levels(const int* __restrict__ parent,
                                                 int* __restrict__ meta,
                                                 int* __restrict__ lstart,
                                                 int* __restrict__ order,
                                                 float* __restrict__ node_h){
  __shared__ int dep[N_NODES];
  __shared__ int dpt[N_NODES];
  __shared__ int cnt[N_NODES];
  __shared__ int changed, maxd;
  const int t = threadIdx.x;
  for(int i=t;i<N_NODES;i+=1024){ dep[i]=parent[i]-1; dpt[i]=0; cnt[i]=0; }
  if(t==0){ maxd=0; }
  node_h[t]=0.f;  // 1024 threads == HID: zero root-parent row
  __syncthreads();
  while(true){
    if(t==0) changed=0;
    __syncthreads();
    bool ch=false;
    for(int i=t;i<N_NODES;i+=1024){
      int d = (dep[i]<0)? 0 : (dpt[dep[i]]+1);
      if(d>dpt[i]){ dpt[i]=d; ch=true; }
    }
    if(ch) changed=1;
    __syncthreads();
    if(!changed) break;
    __syncthreads();
  }
  __syncthreads();
  for(int i=t;i<N_NODES;i+=1024){ atomicAdd(&cnt[dpt[i]],1); atomicMax(&maxd,dpt[i]); }
  __syncthreads();
  // inclusive scan of cnt -> sc (reuse dep)
  int* sc = dep;
  for(int i=t;i<N_NODES;i+=1024) sc[i]=cnt[i];
  __syncthreads();
  for(int off=1; off<N_NODES; off<<=1){
    int v[4];
    #pragma unroll
    for(int u=0;u<4;u++){ int i=t+u*1024; v[u] = (i>=off)? sc[i-off] : 0; }
    __syncthreads();
    #pragma unroll
    for(int u=0;u<4;u++){ int i=t+u*1024; sc[i]+=v[u]; }
    __syncthreads();
  }
  for(int i=t;i<N_NODES;i+=1024) lstart[i+1]=sc[i];
  if(t==0){ lstart[0]=0; meta[0]=maxd+1; }
  // exclusive starts into cnt for scatter
  for(int i=t;i<N_NODES;i+=1024) cnt[i]=sc[i]-cnt[i];
  __syncthreads();
  for(int i=t;i<N_NODES;i+=1024){
    int pos = atomicAdd(&cnt[dpt[i]],1);
    order[pos]=i;
  }
}

// ---------------------------------------------------------------------------
// E [HID][VOCAB] f32  ->  ET [VOCAB][HID] f32  (tiled transpose)
// ---------------------------------------------------------------------------
__global__ __launch_bounds__(256) void k_transpose(const float* __restrict__ E,
                                                   float* __restrict__ ET){
  __shared__ float tile[32][33];
  const int v0 = blockIdx.x*32, h0 = blockIdx.y*32;
  const int tx = threadIdx.x%32, ty = threadIdx.x/32;   // ty 0..7
  #pragma unroll
  for(int i=0;i<4;i++){
    int h = h0+ty+8*i, v = v0+tx;
    tile[ty+8*i][tx] = (v<VOCAB)? E[(size_t)h*VOCAB + v] : 0.f;
  }
  __syncthreads();
  #pragma unroll
  for(int i=0;i<4;i++){
    int v = v0+ty+8*i, h = h0+tx;
    if(v<VOCAB) ET[(size_t)v*HID + h] = tile[tx][ty+8*i];
  }
}

// ---------------------------------------------------------------------------
// xe[n,h] = sum_l w[n,l] * ET[idx[n,l], h]   (one block per node, coalesced)
// ---------------------------------------------------------------------------
__global__ __launch_bounds__(256) void k_xe(const float* __restrict__ ET,
                                            const float* __restrict__ xw,
                                            const int* __restrict__ xi,
                                            float* __restrict__ xe){
  const int n = blockIdx.x;
  __shared__ float w[WPN]; __shared__ int id[WPN];
  const int t = threadIdx.x;
  if(t<WPN){ w[t]=xw[n*WPN+t]; id[t]=xi[n*WPN+t]; }
  __syncthreads();
  const int h0 = t*4;
  float a0=0,a1=0,a2=0,a3=0;
  for(int l=0;l<WPN;l++){
    const float4 e = *(const float4*)(ET + (size_t)id[l]*HID + h0);
    const float wl = w[l];
    a0 += wl*e.x; a1 += wl*e.y; a2 += wl*e.z; a3 += wl*e.w;
  }
  *(float4*)(xe + (size_t)n*HID + h0) = make_float4(a0,a1,a2,a3);
}

// Fallback when ws too small for fp32 ET: direct strided gather from E.
__global__ __launch_bounds__(256) void k_xe_noET(const float* __restrict__ E,
                                                 const float* __restrict__ xw,
                                                 const int* __restrict__ xi,
                                                 float* __restrict__ xe){
  const int n = blockIdx.x;
  __shared__ float w[WPN]; __shared__ int id[WPN];
  const int t = threadIdx.x;
  if(t<WPN){ w[t]=xw[n*WPN+t]; id[t]=xi[n*WPN+t]; }
  __syncthreads();
  const int h0 = t*4;
  float acc[4]={0,0,0,0};
  for(int l=0;l<WPN;l++){
    const float wl=w[l]; const int ix=id[l];
    #pragma unroll
    for(int j=0;j<4;j++) acc[j] += wl*E[(size_t)(h0+j)*VOCAB + ix];
  }
  *(float4*)(xe + (size_t)n*HID + h0) = make_float4(acc[0],acc[1],acc[2],acc[3]);
}

// ---------------------------------------------------------------------------
// Input-side projections: out_g[n,o] = b_g[o] + sum_k xe[n,k]*W_g[o,k]
// 64x64 tile, BK=32, k-major LDS, 4x4 micro-tile.
// ---------------------------------------------------------------------------
__global__ __launch_bounds__(256) void k_gemm_in(const float* __restrict__ xe,
  const float* __restrict__ W0,const float* __restrict__ W1,const float* __restrict__ W2,
  const float* __restrict__ b0,const float* __restrict__ b1,const float* __restrict__ b2,
  float* __restrict__ o0p,float* __restrict__ o1p,float* __restrict__ o2p){
  __shared__ float A[32*68];
  __shared__ float B[32*68];
  const int g=blockIdx.z;
  const float* W  = (g==0)?W0:((g==1)?W1:W2);
  const float* bi = (g==0)?b0:((g==1)?b1:b2);
  float* out      = (g==0)?o0p:((g==1)?o1p:o2p);
  const int n0=blockIdx.x<<6, q0=blockIdx.y<<6;
  const int t=threadIdx.x, tx=t&15, ty=t>>4;
  float acc[4][4]={};
  for(int k0=0;k0<HID;k0+=32){
    #pragma unroll
    for(int m=0;m<2;m++){
      int idx=t+(m<<8); int r=idx>>3; int c4=(idx&7)<<2;
      float4 v=*(const float4*)(xe+(size_t)(n0+r)*HID+k0+c4);
      A[(c4+0)*68+r]=v.x; A[(c4+1)*68+r]=v.y; A[(c4+2)*68+r]=v.z; A[(c4+3)*68+r]=v.w;
      float4 u=*(const float4*)(W+(size_t)(q0+r)*HID+k0+c4);
      B[(c4+0)*68+r]=u.x; B[(c4+1)*68+r]=u.y; B[(c4+2)*68+r]=u.z; B[(c4+3)*68+r]=u.w;
    }
    __syncthreads();
    #pragma unroll 8
    for(int k=0;k<32;k++){
      const float4 a=*(const float4*)&A[k*68+(ty<<2)];
      const float4 b=*(const float4*)&B[k*68+(tx<<2)];
      acc[0][0]+=a.x*b.x; acc[0][1]+=a.x*b.y; acc[0][2]+=a.x*b.z; acc[0][3]+=a.x*b.w;
      acc[1][0]+=a.y*b.x; acc[1][1]+=a.y*b.y; acc[1][2]+=a.y*b.z; acc[1][3]+=a.y*b.w;
      acc[2][0]+=a.z*b.x; acc[2][1]+=a.z*b.y; acc[2][2]+=a.z*b.z; acc[2][3]+=a.z*b.w;
      acc[3][0]+=a.w*b.x; acc[3][1]+=a.w*b.y; acc[3][2]+=a.w*b.z; acc[3][3]+=a.w*b.w;
    }
    __syncthreads();
  }
  const float4 bb=*(const float4*)(bi+q0+(tx<<2));
  #pragma unroll
  for(int i=0;i<4;i++){
    const int n=n0+(ty<<2)+i;
    float4 r4 = make_float4(acc[i][0]+bb.x, acc[i][1]+bb.y, acc[i][2]+bb.z, acc[i][3]+bb.w);
    *(float4*)(out+(size_t)n*HID+q0+(tx<<2)) = r4;
  }
}

// ---------------------------------------------------------------------------
// Persistent level-synchronous recurrence kernel (grid barrier via atomics).
// v2: 512 blocks (2/CU co-resident), 32x32 tasks w/ 2x2 micro-tile so each
// level (~150 nodes) yields 300-600 tasks -> blocks stay busy; latency hidden
// by 8 waves/CU instead of 4.
// ---------------------------------------------------------------------------
__device__ __forceinline__ void gbar(u32* bar, u32 nb){
  __syncthreads();
  if(threadIdx.x==0){
    __threadfence();
    u32* cnt = bar;
    u32* gen = bar+32;   // separate cacheline
    u32 g = __hip_atomic_load(gen, __ATOMIC_RELAXED, __HIP_MEMORY_SCOPE_AGENT);
    u32 a = __hip_atomic_fetch_add(cnt, 1u, __ATOMIC_ACQ_REL, __HIP_MEMORY_SCOPE_AGENT);
    if(a == nb-1u){
      __hip_atomic_store(cnt, 0u, __ATOMIC_RELAXED, __HIP_MEMORY_SCOPE_AGENT);
      __hip_atomic_fetch_add(gen, 1u, __ATOMIC_RELEASE, __HIP_MEMORY_SCOPE_AGENT);
    }else{
      while(__hip_atomic_load(gen, __ATOMIC_ACQUIRE, __HIP_MEMORY_SCOPE_AGENT)==g){
        __builtin_amdgcn_s_sleep(2);
      }
    }
    __threadfence();
  }
  __syncthreads();
}

#define REC_GRID 512

__global__ __launch_bounds__(256,1) void k_rec(
    const int* __restrict__ parent,
    const float* __restrict__ Uz, const float* __restrict__ Ur, const float* __restrict__ Uh,
    float* __restrict__ wz, float* __restrict__ wr, float* __restrict__ wh,
    float* __restrict__ node_h,
    const int* __restrict__ meta, const int* __restrict__ lstart, const int* __restrict__ order,
    u32* __restrict__ bar){
  __shared__ float A[32*36];   // U tile, k-major [k][row], pad->36
  __shared__ float B[32*36];   // PH tile, k-major [k][col]
  __shared__ int nds[32], prw[32];
  const int t=threadIdx.x, tx=t&15, ty=t>>4;
  const u32 nb = gridDim.x;
  const int nlev = meta[0];
  const int r8 = t>>3, c4 = (t&7)<<2;   // load indices: row/col = t>>3 (0..31), 4 k's

  // mode 0: z-gate (wz = sigmoid(wz + Uz@ph))        B rows = node_h[parent]
  // mode 1: r-gate (r=sigmoid(wr+Ur@ph); wr = ph*r)  B rows = node_h[parent]
  // mode 2: h: c=tanh(wh+Uh@(ph*r)); node_h[n+1]=z*ph+(1-z)*c   B rows = wr[n]
  auto task_body = [&](const float* __restrict__ U, const float* __restrict__ Bsrc,
                       const int* __restrict__ bIdx, int mode, int Lj, int ro){
    float acc00=0.f, acc01=0.f, acc10=0.f, acc11=0.f;
    const int bI = bIdx[r8];
    for(int k0=0;k0<HID;k0+=32){
      {
        const float4 v = *(const float4*)(U + (size_t)(ro+r8)*HID + k0+c4);
        A[(c4+0)*36+r8]=v.x; A[(c4+1)*36+r8]=v.y; A[(c4+2)*36+r8]=v.z; A[(c4+3)*36+r8]=v.w;
        const float4 u = *(const float4*)(Bsrc + (size_t)bI*HID + k0+c4);
        B[(c4+0)*36+r8]=u.x; B[(c4+1)*36+r8]=u.y; B[(c4+2)*36+r8]=u.z; B[(c4+3)*36+r8]=u.w;
      }
      __syncthreads();
      #pragma unroll 8
      for(int k=0;k<32;k++){
        const float2 a = *(const float2*)&A[k*36+(ty<<1)];
        const float2 b = *(const float2*)&B[k*36+(tx<<1)];
        acc00 += a.x*b.x; acc01 += a.x*b.y;
        acc10 += a.y*b.x; acc11 += a.y*b.y;
      }
      __syncthreads();
    }
    const int o0 = ro + (ty<<1);
    #pragma unroll
    for(int jj=0;jj<2;jj++){
      const int jl=(tx<<1)+jj;
      const float ac0 = jj? acc01 : acc00;
      const float ac1 = jj? acc11 : acc10;
      if(jl<Lj){
        const int n = nds[jl];
        if(mode==0){
          float* dst = wz + (size_t)n*HID + o0;
          float2 w2 = *(float2*)dst;
          w2.x=sigmf(w2.x+ac0); w2.y=sigmf(w2.y+ac1);
          *(float2*)dst = w2;
        }else if(mode==1){
          float* dst = wr + (size_t)n*HID + o0;
          float2 w2 = *(float2*)dst;
          const float2 ph = *(const float2*)(node_h + (size_t)prw[jl]*HID + o0);
          w2.x=sigmf(w2.x+ac0)*ph.x; w2.y=sigmf(w2.y+ac1)*ph.y;
          *(float2*)dst = w2;
        }else{
          const float2 w2 = *(const float2*)(wh + (size_t)n*HID + o0);
          const float2 z2 = *(const float2*)(wz + (size_t)n*HID + o0);
          const float2 ph = *(const float2*)(node_h + (size_t)prw[jl]*HID + o0);
          float2 hn;
          hn.x = z2.x*ph.x + (1.f-z2.x)*tanhf(w2.x+ac0);
          hn.y = z2.y*ph.y + (1.f-z2.y)*tanhf(w2.y+ac1);
          *(float2*)(node_h + (size_t)(n+1)*HID + o0) = hn;
        }
      }
    }
    __syncthreads();   // protect nds/prw (and LDS) before next task's staging
  };

  for(int lev=0; lev<nlev; ++lev){
    const int s=lstart[lev], e=lstart[lev+1];
    const int L=e-s;
    const int jc=(L+31)>>5;
    // phase A: z and r gates. tasks = 2 gates x 32 rowchunks x jc
    const int tA = jc<<6;
    for(int task=blockIdx.x; task<tA; task+=nb){
      const int jci = task % jc;
      const int rest= task / jc;
      const int rc  = rest & 31;
      const int gate= rest >> 5;
      const int j0  = jci<<5;
      const int Lj  = min(32, L-j0);
      if(t<32){
        int n = (t<Lj)? order[s+j0+t] : 0;
        nds[t]=n; prw[t]=parent[n];
      }
      __syncthreads();
      task_body(gate?Ur:Uz, node_h, prw, gate?1:0, Lj, rc<<5);
    }
    gbar(bar, nb);
    // phase C: h-candidate + state update. tasks = 32 rowchunks x jc
    const int tC = jc<<5;
    for(int task=blockIdx.x; task<tC; task+=nb){
      const int jci = task % jc;
      const int rc  = task / jc;
      const int j0  = jci<<5;
      const int Lj  = min(32, L-j0);
      if(t<32){
        int n = (t<Lj)? order[s+j0+t] : 0;
        nds[t]=n; prw[t]=parent[n];
      }
      __syncthreads();
      task_body(Uh, wr, nds, 2, Lj, rc<<5);
    }
    gbar(bar, nb);
  }
}

// ---------------------------------------------------------------------------
// Leaf max + softmax + loss. Output: FP32 pred[4], loss.
// ---------------------------------------------------------------------------
__global__ __launch_bounds__(1024) void k_final(const float* __restrict__ node_h,
                                                const int* __restrict__ leaf,
                                                const float* __restrict__ Wout,
                                                const float* __restrict__ bout,
                                                const float* __restrict__ y,
                                                float* __restrict__ out){
  __shared__ int li[NLEAVES];
  __shared__ float fs[HID];
  __shared__ float logits[NCLASS];
  const int t=threadIdx.x;
  li[t]=leaf[t];
  __syncthreads();
  float m=-INFINITY;
  for(int l=0;l<NLEAVES;l++) m = fmaxf(m, node_h[(size_t)li[l]*HID + t]);
  fs[t]=m;
  __syncthreads();
  const int wave=t>>6, lane=t&63;
  if(wave<NCLASS){
    float p=0.f;
    for(int h=lane;h<HID;h+=64) p += Wout[wave*HID+h]*fs[h];
    for(int off=32; off; off>>=1) p += __shfl_down(p, off);
    if(lane==0) logits[wave]=p+bout[wave];
  }
  __syncthreads();
  if(t==0){
    float mx = fmaxf(fmaxf(logits[0],logits[1]),fmaxf(logits[2],logits[3]));
    float ev[NCLASS]; float es=0.f;
    #pragma unroll
    for(int c=0;c<NCLASS;c++){ ev[c]=expf(logits[c]-mx); es+=ev[c]; }
    float loss=0.f;
    #pragma unroll
    for(int c=0;c<NCLASS;c++){
      float p=ev[c]/es;
      out[c]=p;
      float d=y[c]-p; loss+=d*d;
    }
    out[NCLASS]=loss;
  }
}

// ---------------------------------------------------------------------------
extern "C" void kernel_launch(void* const* d_in, const int* in_sizes, int n_in,
                              void* d_out, int out_size, void* d_ws, size_t ws_size,
                              hipStream_t stream){
  (void)in_sizes; (void)n_in; (void)out_size;
  const float* x_word=(const float*)d_in[0];
  const int*   x_index=(const int*)d_in[1];
  const int*   parent =(const int*)d_in[2];
  const int*   leaf   =(const int*)d_in[3];
  const float* y      =(const float*)d_in[4];
  const float* E      =(const float*)d_in[5];
  const float* W_z=(const float*)d_in[6];  const float* U_z=(const float*)d_in[7];  const float* b_z=(const float*)d_in[8];
  const float* W_r=(const float*)d_in[9];  const float* U_r=(const float*)d_in[10]; const float* b_r=(const float*)d_in[11];
  const float* W_h=(const float*)d_in[12]; const float* U_h=(const float*)d_in[13]; const float* b_h=(const float*)d_in[14];
  const float* W_out=(const float*)d_in[15]; const float* b_out=(const float*)d_in[16];

  size_t off=0;
  char* wsb=(char*)d_ws;
  auto alloc=[&](size_t b)->void*{ void* p=wsb+off; off=(off+b+255)&~(size_t)255; return p; };
  u32*  bar    = (u32*)  alloc(256);
  int*  meta   = (int*)  alloc(256);
  int*  lstart = (int*)  alloc((N_NODES+1)*sizeof(int));
  int*  order  = (int*)  alloc(N_NODES*sizeof(int));
  float* node_h= (float*)alloc((size_t)(N_NODES+1)*HID*sizeof(float));
  float* xe    = (float*)alloc((size_t)N_NODES*HID*sizeof(float));
  float* wz    = (float*)alloc((size_t)N_NODES*HID*sizeof(float));
  float* wr    = (float*)alloc((size_t)N_NODES*HID*sizeof(float));
  float* wh    = (float*)alloc((size_t)N_NODES*HID*sizeof(float));
  float* ET    = (float*)(wsb+off);
  const size_t need_ET = off + (size_t)VOCAB*HID*sizeof(float);
  const bool useET = (ws_size >= need_ET);

  hipMemsetAsync(bar, 0, 256, stream);
  k_levels<<<1,1024,0,stream>>>(parent, meta, lstart, order, node_h);
  if(useET){
    k_transpose<<<dim3((VOCAB+31)/32, HID/32),256,0,stream>>>(E, ET);
    k_xe<<<N_NODES,256,0,stream>>>(ET, x_word, x_index, xe);
  }else{
    k_xe_noET<<<N_NODES,256,0,stream>>>(E, x_word, x_index, xe);
  }
  k_gemm_in<<<dim3(N_NODES/64, HID/64, 3),256,0,stream>>>(xe, W_z,W_r,W_h, b_z,b_r,b_h, wz,wr,wh);
  k_rec<<<REC_GRID,256,0,stream>>>(parent, U_z,U_r,U_h, wz,wr,wh, node_h, meta, lstart, order, bar);
  k_final<<<1,1024,0,stream>>>(node_h, leaf, W_out, b_out, y, (float*)d_out);
}

// Round 5
// 5319.484 us; speedup vs baseline: 1.1131x; 1.1001x over previous
//
#include <hip/hip_runtime.h>
#include <hip/hip_bf16.h>
#include <math.h>

#define N_NODES 4096
#define WPN 32
#define HID 1024
#define VOCAB 30000
#define NCLASS 4
#define NLEAVES 1024

typedef unsigned int u32;
typedef unsigned short u16;

__device__ __forceinline__ float sigmf(float x){ return 1.f/(1.f+expf(-x)); }

// ---------------------------------------------------------------------------
// Level schedule: depth[i] via iterative relaxation in LDS, then counting sort.
// Also zeroes node_h row 0 (root parent).
// ---------------------------------------------------------------------------
__global__ __launch_bounds__(1024) void k_levels(const int* __restrict__ parent,
                                                 int* __restrict__ meta,
                                                 int* __restrict__ lstart,
                                                 int* __restrict__ order,
                                                 float* __restrict__ node_h){
  __shared__ int dep[N_NODES];
  __shared__ int dpt[N_NODES];
  __shared__ int cnt[N_NODES];
  __shared__ int changed, maxd;
  const int t = threadIdx.x;
  for(int i=t;i<N_NODES;i+=1024){ dep[i]=parent[i]-1; dpt[i]=0; cnt[i]=0; }
  if(t==0){ maxd=0; }
  node_h[t]=0.f;  // 1024 threads == HID: zero root-parent row
  __syncthreads();
  while(true){
    if(t==0) changed=0;
    __syncthreads();
    bool ch=false;
    for(int i=t;i<N_NODES;i+=1024){
      int d = (dep[i]<0)? 0 : (dpt[dep[i]]+1);
      if(d>dpt[i]){ dpt[i]=d; ch=true; }
    }
    if(ch) changed=1;
    __syncthreads();
    if(!changed) break;
    __syncthreads();
  }
  __syncthreads();
  for(int i=t;i<N_NODES;i+=1024){ atomicAdd(&cnt[dpt[i]],1); atomicMax(&maxd,dpt[i]); }
  __syncthreads();
  // inclusive scan of cnt -> sc (reuse dep)
  int* sc = dep;
  for(int i=t;i<N_NODES;i+=1024) sc[i]=cnt[i];
  __syncthreads();
  for(int off=1; off<N_NODES; off<<=1){
    int v[4];
    #pragma unroll
    for(int u=0;u<4;u++){ int i=t+u*1024; v[u] = (i>=off)? sc[i-off] : 0; }
    __syncthreads();
    #pragma unroll
    for(int u=0;u<4;u++){ int i=t+u*1024; sc[i]+=v[u]; }
    __syncthreads();
  }
  for(int i=t;i<N_NODES;i+=1024) lstart[i+1]=sc[i];
  if(t==0){ lstart[0]=0; meta[0]=maxd+1; }
  // exclusive starts into cnt for scatter
  for(int i=t;i<N_NODES;i+=1024) cnt[i]=sc[i]-cnt[i];
  __syncthreads();
  for(int i=t;i<N_NODES;i+=1024){
    int pos = atomicAdd(&cnt[dpt[i]],1);
    order[pos]=i;
  }
}

// ---------------------------------------------------------------------------
// E [HID][VOCAB] f32  ->  ET [VOCAB][HID] f32  (tiled transpose)
// ---------------------------------------------------------------------------
__global__ __launch_bounds__(256) void k_transpose(const float* __restrict__ E,
                                                   float* __restrict__ ET){
  __shared__ float tile[32][33];
  const int v0 = blockIdx.x*32, h0 = blockIdx.y*32;
  const int tx = threadIdx.x%32, ty = threadIdx.x/32;   // ty 0..7
  #pragma unroll
  for(int i=0;i<4;i++){
    int h = h0+ty+8*i, v = v0+tx;
    tile[ty+8*i][tx] = (v<VOCAB)? E[(size_t)h*VOCAB + v] : 0.f;
  }
  __syncthreads();
  #pragma unroll
  for(int i=0;i<4;i++){
    int v = v0+ty+8*i, h = h0+tx;
    if(v<VOCAB) ET[(size_t)v*HID + h] = tile[tx][ty+8*i];
  }
}

// ---------------------------------------------------------------------------
// xe[n,h] = sum_l w[n,l] * ET[idx[n,l], h]   (one block per node, coalesced)
// ---------------------------------------------------------------------------
__global__ __launch_bounds__(256) void k_xe(const float* __restrict__ ET,
                                            const float* __restrict__ xw,
                                            const int* __restrict__ xi,
                                            float* __restrict__ xe){
  const int n = blockIdx.x;
  __shared__ float w[WPN]; __shared__ int id[WPN];
  const int t = threadIdx.x;
  if(t<WPN){ w[t]=xw[n*WPN+t]; id[t]=xi[n*WPN+t]; }
  __syncthreads();
  const int h0 = t*4;
  float a0=0,a1=0,a2=0,a3=0;
  for(int l=0;l<WPN;l++){
    const float4 e = *(const float4*)(ET + (size_t)id[l]*HID + h0);
    const float wl = w[l];
    a0 += wl*e.x; a1 += wl*e.y; a2 += wl*e.z; a3 += wl*e.w;
  }
  *(float4*)(xe + (size_t)n*HID + h0) = make_float4(a0,a1,a2,a3);
}

// Fallback when ws too small for fp32 ET: direct strided gather from E.
__global__ __launch_bounds__(256) void k_xe_noET(const float* __restrict__ E,
                                                 const float* __restrict__ xw,
                                                 const int* __restrict__ xi,
                                                 float* __restrict__ xe){
  const int n = blockIdx.x;
  __shared__ float w[WPN]; __shared__ int id[WPN];
  const int t = threadIdx.x;
  if(t<WPN){ w[t]=xw[n*WPN+t]; id[t]=xi[n*WPN+t]; }
  __syncthreads();
  const int h0 = t*4;
  float acc[4]={0,0,0,0};
  for(int l=0;l<WPN;l++){
    const float wl=w[l]; const int ix=id[l];
    #pragma unroll
    for(int j=0;j<4;j++) acc[j] += wl*E[(size_t)(h0+j)*VOCAB + ix];
  }
  *(float4*)(xe + (size_t)n*HID + h0) = make_float4(acc[0],acc[1],acc[2],acc[3]);
}

// ---------------------------------------------------------------------------
// Input-side projections: out_g[n,o] = b_g[o] + sum_k xe[n,k]*W_g[o,k]
// 64x64 tile, BK=32, k-major LDS, 4x4 micro-tile.
// ---------------------------------------------------------------------------
__global__ __launch_bounds__(256) void k_gemm_in(const float* __restrict__ xe,
  const float* __restrict__ W0,const float* __restrict__ W1,const float* __restrict__ W2,
  const float* __restrict__ b0,const float* __restrict__ b1,const float* __restrict__ b2,
  float* __restrict__ o0p,float* __restrict__ o1p,float* __restrict__ o2p){
  __shared__ float A[32*68];
  __shared__ float B[32*68];
  const int g=blockIdx.z;
  const float* W  = (g==0)?W0:((g==1)?W1:W2);
  const float* bi = (g==0)?b0:((g==1)?b1:b2);
  float* out      = (g==0)?o0p:((g==1)?o1p:o2p);
  const int n0=blockIdx.x<<6, q0=blockIdx.y<<6;
  const int t=threadIdx.x, tx=t&15, ty=t>>4;
  float acc[4][4]={};
  for(int k0=0;k0<HID;k0+=32){
    #pragma unroll
    for(int m=0;m<2;m++){
      int idx=t+(m<<8); int r=idx>>3; int c4=(idx&7)<<2;
      float4 v=*(const float4*)(xe+(size_t)(n0+r)*HID+k0+c4);
      A[(c4+0)*68+r]=v.x; A[(c4+1)*68+r]=v.y; A[(c4+2)*68+r]=v.z; A[(c4+3)*68+r]=v.w;
      float4 u=*(const float4*)(W+(size_t)(q0+r)*HID+k0+c4);
      B[(c4+0)*68+r]=u.x; B[(c4+1)*68+r]=u.y; B[(c4+2)*68+r]=u.z; B[(c4+3)*68+r]=u.w;
    }
    __syncthreads();
    #pragma unroll 8
    for(int k=0;k<32;k++){
      const float4 a=*(const float4*)&A[k*68+(ty<<2)];
      const float4 b=*(const float4*)&B[k*68+(tx<<2)];
      acc[0][0]+=a.x*b.x; acc[0][1]+=a.x*b.y; acc[0][2]+=a.x*b.z; acc[0][3]+=a.x*b.w;
      acc[1][0]+=a.y*b.x; acc[1][1]+=a.y*b.y; acc[1][2]+=a.y*b.z; acc[1][3]+=a.y*b.w;
      acc[2][0]+=a.z*b.x; acc[2][1]+=a.z*b.y; acc[2][2]+=a.z*b.z; acc[2][3]+=a.z*b.w;
      acc[3][0]+=a.w*b.x; acc[3][1]+=a.w*b.y; acc[3][2]+=a.w*b.z; acc[3][3]+=a.w*b.w;
    }
    __syncthreads();
  }
  const float4 bb=*(const float4*)(bi+q0+(tx<<2));
  #pragma unroll
  for(int i=0;i<4;i++){
    const int n=n0+(ty<<2)+i;
    float4 r4 = make_float4(acc[i][0]+bb.x, acc[i][1]+bb.y, acc[i][2]+bb.z, acc[i][3]+bb.w);
    *(float4*)(out+(size_t)n*HID+q0+(tx<<2)) = r4;
  }
}

// ---------------------------------------------------------------------------
// Persistent level-synchronous recurrence kernel.
// v3: TREE grid barrier (16 groups x 32 blocks -> root -> gen) + s_sleep(16)
// backoff: round-4 counters showed ~60 flat barriers at 512 blocks cost
// ~90us each (603MB of FETCH = spin polls on one hot line, dur==FETCH/128GB/s
// for two structurally different kernels). Also: register double-buffer of
// the next k-tile to shorten the per-task latency chain.
// ---------------------------------------------------------------------------
#define REC_GRID 512
#define GRPSH 5
#define GRP   (1<<GRPSH)            // 32 blocks per group
#define NGRP  (REC_GRID>>GRPSH)     // 16 groups

__device__ __forceinline__ void gbar(u32* bar){
  // layout (u32): bar[0]=gen | bar[16+g*16]=group g cnt | bar[16+NGRP*16]=root
  __syncthreads();
  if(threadIdx.x==0){
    __threadfence();
    u32* gen  = bar;
    u32* gcnt = bar + 16 + ((blockIdx.x>>GRPSH)<<4);
    u32* root = bar + 16 + (NGRP<<4);
    u32 g = __hip_atomic_load(gen, __ATOMIC_RELAXED, __HIP_MEMORY_SCOPE_AGENT);
    u32 a = __hip_atomic_fetch_add(gcnt, 1u, __ATOMIC_ACQ_REL, __HIP_MEMORY_SCOPE_AGENT);
    if(a == GRP-1u){
      __hip_atomic_store(gcnt, 0u, __ATOMIC_RELAXED, __HIP_MEMORY_SCOPE_AGENT);
      u32 b = __hip_atomic_fetch_add(root, 1u, __ATOMIC_ACQ_REL, __HIP_MEMORY_SCOPE_AGENT);
      if(b == NGRP-1u){
        __hip_atomic_store(root, 0u, __ATOMIC_RELAXED, __HIP_MEMORY_SCOPE_AGENT);
        __hip_atomic_fetch_add(gen, 1u, __ATOMIC_RELEASE, __HIP_MEMORY_SCOPE_AGENT);
      }
    }
    while(__hip_atomic_load(gen, __ATOMIC_ACQUIRE, __HIP_MEMORY_SCOPE_AGENT)==g){
      __builtin_amdgcn_s_sleep(16);
    }
    __threadfence();
  }
  __syncthreads();
}

__global__ __launch_bounds__(256,1) void k_rec(
    const int* __restrict__ parent,
    const float* __restrict__ Uz, const float* __restrict__ Ur, const float* __restrict__ Uh,
    float* __restrict__ wz, float* __restrict__ wr, float* __restrict__ wh,
    float* __restrict__ node_h,
    const int* __restrict__ meta, const int* __restrict__ lstart, const int* __restrict__ order,
    u32* __restrict__ bar){
  __shared__ float A[32*36];   // U tile, k-major [k][row], pad->36
  __shared__ float B[32*36];   // PH tile, k-major [k][col]
  __shared__ int nds[32], prw[32];
  const int t=threadIdx.x, tx=t&15, ty=t>>4;
  const u32 nb = gridDim.x;
  const int nlev = meta[0];
  const int r8 = t>>3, c4 = (t&7)<<2;

  // mode 0: z-gate (wz = sigmoid(wz + Uz@ph))        B rows = node_h[parent]
  // mode 1: r-gate (r=sigmoid(wr+Ur@ph); wr = ph*r)  B rows = node_h[parent]
  // mode 2: h: c=tanh(wh+Uh@(ph*r)); node_h[n+1]=z*ph+(1-z)*c   B rows = wr[n]
  auto task_body = [&](const float* __restrict__ U, const float* __restrict__ Bsrc,
                       const int* __restrict__ bIdx, int mode, int Lj, int ro){
    float acc00=0.f, acc01=0.f, acc10=0.f, acc11=0.f;
    const float* uRow = U + (size_t)(ro+r8)*HID + c4;
    const float* bRow = Bsrc + (size_t)bIdx[r8]*HID + c4;
    float4 Av = *(const float4*)(uRow);
    float4 Bv = *(const float4*)(bRow);
    for(int k0=0;k0<HID;k0+=32){
      A[(c4+0)*36+r8]=Av.x; A[(c4+1)*36+r8]=Av.y; A[(c4+2)*36+r8]=Av.z; A[(c4+3)*36+r8]=Av.w;
      B[(c4+0)*36+r8]=Bv.x; B[(c4+1)*36+r8]=Bv.y; B[(c4+2)*36+r8]=Bv.z; B[(c4+3)*36+r8]=Bv.w;
      __syncthreads();
      if(k0+32<HID){                 // prefetch next tile during compute
        Av = *(const float4*)(uRow + k0+32);
        Bv = *(const float4*)(bRow + k0+32);
      }
      #pragma unroll 8
      for(int k=0;k<32;k++){
        const float2 a = *(const float2*)&A[k*36+(ty<<1)];
        const float2 b = *(const float2*)&B[k*36+(tx<<1)];
        acc00 += a.x*b.x; acc01 += a.x*b.y;
        acc10 += a.y*b.x; acc11 += a.y*b.y;
      }
      __syncthreads();
    }
    const int o0 = ro + (ty<<1);
    #pragma unroll
    for(int jj=0;jj<2;jj++){
      const int jl=(tx<<1)+jj;
      const float ac0 = jj? acc01 : acc00;
      const float ac1 = jj? acc11 : acc10;
      if(jl<Lj){
        const int n = nds[jl];
        if(mode==0){
          float* dst = wz + (size_t)n*HID + o0;
          float2 w2 = *(float2*)dst;
          w2.x=sigmf(w2.x+ac0); w2.y=sigmf(w2.y+ac1);
          *(float2*)dst = w2;
        }else if(mode==1){
          float* dst = wr + (size_t)n*HID + o0;
          float2 w2 = *(float2*)dst;
          const float2 ph = *(const float2*)(node_h + (size_t)prw[jl]*HID + o0);
          w2.x=sigmf(w2.x+ac0)*ph.x; w2.y=sigmf(w2.y+ac1)*ph.y;
          *(float2*)dst = w2;
        }else{
          const float2 w2 = *(const float2*)(wh + (size_t)n*HID + o0);
          const float2 z2 = *(const float2*)(wz + (size_t)n*HID + o0);
          const float2 ph = *(const float2*)(node_h + (size_t)prw[jl]*HID + o0);
          float2 hn;
          hn.x = z2.x*ph.x + (1.f-z2.x)*tanhf(w2.x+ac0);
          hn.y = z2.y*ph.y + (1.f-z2.y)*tanhf(w2.y+ac1);
          *(float2*)(node_h + (size_t)(n+1)*HID + o0) = hn;
        }
      }
    }
    __syncthreads();   // protect nds/prw (and LDS) before next task's staging
  };

  for(int lev=0; lev<nlev; ++lev){
    const int s=lstart[lev], e=lstart[lev+1];
    const int L=e-s;
    const int jc=(L+31)>>5;
    // phase A: z and r gates. tasks = 2 gates x 32 rowchunks x jc
    const int tA = jc<<6;
    for(int task=blockIdx.x; task<tA; task+=nb){
      const int jci = task % jc;
      const int rest= task / jc;
      const int rc  = rest & 31;
      const int gate= rest >> 5;
      const int j0  = jci<<5;
      const int Lj  = min(32, L-j0);
      if(t<32){
        int n = (t<Lj)? order[s+j0+t] : 0;
        nds[t]=n; prw[t]=parent[n];
      }
      __syncthreads();
      task_body(gate?Ur:Uz, node_h, prw, gate?1:0, Lj, rc<<5);
    }
    gbar(bar);
    // phase C: h-candidate + state update. tasks = 32 rowchunks x jc
    const int tC = jc<<5;
    for(int task=blockIdx.x; task<tC; task+=nb){
      const int jci = task % jc;
      const int rc  = task / jc;
      const int j0  = jci<<5;
      const int Lj  = min(32, L-j0);
      if(t<32){
        int n = (t<Lj)? order[s+j0+t] : 0;
        nds[t]=n; prw[t]=parent[n];
      }
      __syncthreads();
      task_body(Uh, wr, nds, 2, Lj, rc<<5);
    }
    gbar(bar);
  }
}

// ---------------------------------------------------------------------------
// Leaf max + softmax + loss. Output: FP32 pred[4], loss.
// ---------------------------------------------------------------------------
__global__ __launch_bounds__(1024) void k_final(const float* __restrict__ node_h,
                                                const int* __restrict__ leaf,
                                                const float* __restrict__ Wout,
                                                const float* __restrict__ bout,
                                                const float* __restrict__ y,
                                                float* __restrict__ out){
  __shared__ int li[NLEAVES];
  __shared__ float fs[HID];
  __shared__ float logits[NCLASS];
  const int t=threadIdx.x;
  li[t]=leaf[t];
  __syncthreads();
  float m=-INFINITY;
  for(int l=0;l<NLEAVES;l++) m = fmaxf(m, node_h[(size_t)li[l]*HID + t]);
  fs[t]=m;
  __syncthreads();
  const int wave=t>>6, lane=t&63;
  if(wave<NCLASS){
    float p=0.f;
    for(int h=lane;h<HID;h+=64) p += Wout[wave*HID+h]*fs[h];
    for(int off=32; off; off>>=1) p += __shfl_down(p, off);
    if(lane==0) logits[wave]=p+bout[wave];
  }
  __syncthreads();
  if(t==0){
    float mx = fmaxf(fmaxf(logits[0],logits[1]),fmaxf(logits[2],logits[3]));
    float ev[NCLASS]; float es=0.f;
    #pragma unroll
    for(int c=0;c<NCLASS;c++){ ev[c]=expf(logits[c]-mx); es+=ev[c]; }
    float loss=0.f;
    #pragma unroll
    for(int c=0;c<NCLASS;c++){
      float p=ev[c]/es;
      out[c]=p;
      float d=y[c]-p; loss+=d*d;
    }
    out[NCLASS]=loss;
  }
}

// ---------------------------------------------------------------------------
extern "C" void kernel_launch(void* const* d_in, const int* in_sizes, int n_in,
                              void* d_out, int out_size, void* d_ws, size_t ws_size,
                              hipStream_t stream){
  (void)in_sizes; (void)n_in; (void)out_size;
  const float* x_word=(const float*)d_in[0];
  const int*   x_index=(const int*)d_in[1];
  const int*   parent =(const int*)d_in[2];
  const int*   leaf   =(const int*)d_in[3];
  const float* y      =(const float*)d_in[4];
  const float* E      =(const float*)d_in[5];
  const float* W_z=(const float*)d_in[6];  const float* U_z=(const float*)d_in[7];  const float* b_z=(const float*)d_in[8];
  const float* W_r=(const float*)d_in[9];  const float* U_r=(const float*)d_in[10]; const float* b_r=(const float*)d_in[11];
  const float* W_h=(const float*)d_in[12]; const float* U_h=(const float*)d_in[13]; const float* b_h=(const float*)d_in[14];
  const float* W_out=(const float*)d_in[15]; const float* b_out=(const float*)d_in[16];

  size_t off=0;
  char* wsb=(char*)d_ws;
  auto alloc=[&](size_t b)->void*{ void* p=wsb+off; off=(off+b+255)&~(size_t)255; return p; };
  u32*  bar    = (u32*)  alloc(4096);
  int*  meta   = (int*)  alloc(256);
  int*  lstart = (int*)  alloc((N_NODES+1)*sizeof(int));
  int*  order  = (int*)  alloc(N_NODES*sizeof(int));
  float* node_h= (float*)alloc((size_t)(N_NODES+1)*HID*sizeof(float));
  float* xe    = (float*)alloc((size_t)N_NODES*HID*sizeof(float));
  float* wz    = (float*)alloc((size_t)N_NODES*HID*sizeof(float));
  float* wr    = (float*)alloc((size_t)N_NODES*HID*sizeof(float));
  float* wh    = (float*)alloc((size_t)N_NODES*HID*sizeof(float));
  float* ET    = (float*)(wsb+off);
  const size_t need_ET = off + (size_t)VOCAB*HID*sizeof(float);
  const bool useET = (ws_size >= need_ET);

  hipMemsetAsync(bar, 0, 4096, stream);
  k_levels<<<1,1024,0,stream>>>(parent, meta, lstart, order, node_h);
  if(useET){
    k_transpose<<<dim3((VOCAB+31)/32, HID/32),256,0,stream>>>(E, ET);
    k_xe<<<N_NODES,256,0,stream>>>(ET, x_word, x_index, xe);
  }else{
    k_xe_noET<<<N_NODES,256,0,stream>>>(E, x_word, x_index, xe);
  }
  k_gemm_in<<<dim3(N_NODES/64, HID/64, 3),256,0,stream>>>(xe, W_z,W_r,W_h, b_z,b_r,b_h, wz,wr,wh);
  k_rec<<<REC_GRID,256,0,stream>>>(parent, U_z,U_r,U_h, wz,wr,wh, node_h, meta, lstart, order, bar);
  k_final<<<1,1024,0,stream>>>(node_h, leaf, W_out, b_out, y, (float*)d_out);
}

// Round 6
// 2977.191 us; speedup vs baseline: 1.9888x; 1.7867x over previous
//
#include <hip/hip_runtime.h>
#include <hip/hip_bf16.h>
#include <math.h>

#define N_NODES 4096
#define WPN 32
#define HID 1024
#define VOCAB 30000
#define NCLASS 4
#define NLEAVES 1024

typedef unsigned int u32;
typedef unsigned short u16;

__device__ __forceinline__ float sigmf(float x){ return 1.f/(1.f+expf(-x)); }

// ---------------------------------------------------------------------------
// Level schedule: depth[i] via iterative relaxation in LDS, then counting sort.
// Also zeroes node_h row 0 (root parent).
// ---------------------------------------------------------------------------
__global__ __launch_bounds__(1024) void k_levels(const int* __restrict__ parent,
                                                 int* __restrict__ meta,
                                                 int* __restrict__ lstart,
                                                 int* __restrict__ order,
                                                 float* __restrict__ node_h){
  __shared__ int dep[N_NODES];
  __shared__ int dpt[N_NODES];
  __shared__ int cnt[N_NODES];
  __shared__ int changed, maxd;
  const int t = threadIdx.x;
  for(int i=t;i<N_NODES;i+=1024){ dep[i]=parent[i]-1; dpt[i]=0; cnt[i]=0; }
  if(t==0){ maxd=0; }
  node_h[t]=0.f;  // 1024 threads == HID: zero root-parent row
  __syncthreads();
  while(true){
    if(t==0) changed=0;
    __syncthreads();
    bool ch=false;
    for(int i=t;i<N_NODES;i+=1024){
      int d = (dep[i]<0)? 0 : (dpt[dep[i]]+1);
      if(d>dpt[i]){ dpt[i]=d; ch=true; }
    }
    if(ch) changed=1;
    __syncthreads();
    if(!changed) break;
    __syncthreads();
  }
  __syncthreads();
  for(int i=t;i<N_NODES;i+=1024){ atomicAdd(&cnt[dpt[i]],1); atomicMax(&maxd,dpt[i]); }
  __syncthreads();
  // inclusive scan of cnt -> sc (reuse dep)
  int* sc = dep;
  for(int i=t;i<N_NODES;i+=1024) sc[i]=cnt[i];
  __syncthreads();
  for(int off=1; off<N_NODES; off<<=1){
    int v[4];
    #pragma unroll
    for(int u=0;u<4;u++){ int i=t+u*1024; v[u] = (i>=off)? sc[i-off] : 0; }
    __syncthreads();
    #pragma unroll
    for(int u=0;u<4;u++){ int i=t+u*1024; sc[i]+=v[u]; }
    __syncthreads();
  }
  for(int i=t;i<N_NODES;i+=1024) lstart[i+1]=sc[i];
  if(t==0){ lstart[0]=0; meta[0]=maxd+1; }
  // exclusive starts into cnt for scatter
  for(int i=t;i<N_NODES;i+=1024) cnt[i]=sc[i]-cnt[i];
  __syncthreads();
  for(int i=t;i<N_NODES;i+=1024){
    int pos = atomicAdd(&cnt[dpt[i]],1);
    order[pos]=i;
  }
}

// ---------------------------------------------------------------------------
// E [HID][VOCAB] f32  ->  ET [VOCAB][HID] f32  (tiled transpose)
// ---------------------------------------------------------------------------
__global__ __launch_bounds__(256) void k_transpose(const float* __restrict__ E,
                                                   float* __restrict__ ET){
  __shared__ float tile[32][33];
  const int v0 = blockIdx.x*32, h0 = blockIdx.y*32;
  const int tx = threadIdx.x%32, ty = threadIdx.x/32;   // ty 0..7
  #pragma unroll
  for(int i=0;i<4;i++){
    int h = h0+ty+8*i, v = v0+tx;
    tile[ty+8*i][tx] = (v<VOCAB)? E[(size_t)h*VOCAB + v] : 0.f;
  }
  __syncthreads();
  #pragma unroll
  for(int i=0;i<4;i++){
    int v = v0+ty+8*i, h = h0+tx;
    if(v<VOCAB) ET[(size_t)v*HID + h] = tile[tx][ty+8*i];
  }
}

// ---------------------------------------------------------------------------
// xe[n,h] = sum_l w[n,l] * ET[idx[n,l], h]   (one block per node, coalesced)
// ---------------------------------------------------------------------------
__global__ __launch_bounds__(256) void k_xe(const float* __restrict__ ET,
                                            const float* __restrict__ xw,
                                            const int* __restrict__ xi,
                                            float* __restrict__ xe){
  const int n = blockIdx.x;
  __shared__ float w[WPN]; __shared__ int id[WPN];
  const int t = threadIdx.x;
  if(t<WPN){ w[t]=xw[n*WPN+t]; id[t]=xi[n*WPN+t]; }
  __syncthreads();
  const int h0 = t*4;
  float a0=0,a1=0,a2=0,a3=0;
  for(int l=0;l<WPN;l++){
    const float4 e = *(const float4*)(ET + (size_t)id[l]*HID + h0);
    const float wl = w[l];
    a0 += wl*e.x; a1 += wl*e.y; a2 += wl*e.z; a3 += wl*e.w;
  }
  *(float4*)(xe + (size_t)n*HID + h0) = make_float4(a0,a1,a2,a3);
}

// Fallback when ws too small for fp32 ET: direct strided gather from E.
__global__ __launch_bounds__(256) void k_xe_noET(const float* __restrict__ E,
                                                 const float* __restrict__ xw,
                                                 const int* __restrict__ xi,
                                                 float* __restrict__ xe){
  const int n = blockIdx.x;
  __shared__ float w[WPN]; __shared__ int id[WPN];
  const int t = threadIdx.x;
  if(t<WPN){ w[t]=xw[n*WPN+t]; id[t]=xi[n*WPN+t]; }
  __syncthreads();
  const int h0 = t*4;
  float acc[4]={0,0,0,0};
  for(int l=0;l<WPN;l++){
    const float wl=w[l]; const int ix=id[l];
    #pragma unroll
    for(int j=0;j<4;j++) acc[j] += wl*E[(size_t)(h0+j)*VOCAB + ix];
  }
  *(float4*)(xe + (size_t)n*HID + h0) = make_float4(acc[0],acc[1],acc[2],acc[3]);
}

// ---------------------------------------------------------------------------
// Input-side projections: out_g[n,o] = b_g[o] + sum_k xe[n,k]*W_g[o,k]
// 64x64 tile, BK=32, k-major LDS, 4x4 micro-tile.
// ---------------------------------------------------------------------------
__global__ __launch_bounds__(256) void k_gemm_in(const float* __restrict__ xe,
  const float* __restrict__ W0,const float* __restrict__ W1,const float* __restrict__ W2,
  const float* __restrict__ b0,const float* __restrict__ b1,const float* __restrict__ b2,
  float* __restrict__ o0p,float* __restrict__ o1p,float* __restrict__ o2p){
  __shared__ float A[32*68];
  __shared__ float B[32*68];
  const int g=blockIdx.z;
  const float* W  = (g==0)?W0:((g==1)?W1:W2);
  const float* bi = (g==0)?b0:((g==1)?b1:b2);
  float* out      = (g==0)?o0p:((g==1)?o1p:o2p);
  const int n0=blockIdx.x<<6, q0=blockIdx.y<<6;
  const int t=threadIdx.x, tx=t&15, ty=t>>4;
  float acc[4][4]={};
  for(int k0=0;k0<HID;k0+=32){
    #pragma unroll
    for(int m=0;m<2;m++){
      int idx=t+(m<<8); int r=idx>>3; int c4=(idx&7)<<2;
      float4 v=*(const float4*)(xe+(size_t)(n0+r)*HID+k0+c4);
      A[(c4+0)*68+r]=v.x; A[(c4+1)*68+r]=v.y; A[(c4+2)*68+r]=v.z; A[(c4+3)*68+r]=v.w;
      float4 u=*(const float4*)(W+(size_t)(q0+r)*HID+k0+c4);
      B[(c4+0)*68+r]=u.x; B[(c4+1)*68+r]=u.y; B[(c4+2)*68+r]=u.z; B[(c4+3)*68+r]=u.w;
    }
    __syncthreads();
    #pragma unroll 8
    for(int k=0;k<32;k++){
      const float4 a=*(const float4*)&A[k*68+(ty<<2)];
      const float4 b=*(const float4*)&B[k*68+(tx<<2)];
      acc[0][0]+=a.x*b.x; acc[0][1]+=a.x*b.y; acc[0][2]+=a.x*b.z; acc[0][3]+=a.x*b.w;
      acc[1][0]+=a.y*b.x; acc[1][1]+=a.y*b.y; acc[1][2]+=a.y*b.z; acc[1][3]+=a.y*b.w;
      acc[2][0]+=a.z*b.x; acc[2][1]+=a.z*b.y; acc[2][2]+=a.z*b.z; acc[2][3]+=a.z*b.w;
      acc[3][0]+=a.w*b.x; acc[3][1]+=a.w*b.y; acc[3][2]+=a.w*b.z; acc[3][3]+=a.w*b.w;
    }
    __syncthreads();
  }
  const float4 bb=*(const float4*)(bi+q0+(tx<<2));
  #pragma unroll
  for(int i=0;i<4;i++){
    const int n=n0+(ty<<2)+i;
    float4 r4 = make_float4(acc[i][0]+bb.x, acc[i][1]+bb.y, acc[i][2]+bb.z, acc[i][3]+bb.w);
    *(float4*)(out+(size_t)n*HID+q0+(tx<<2)) = r4;
  }
}

// ---------------------------------------------------------------------------
// Persistent level-synchronous recurrence, v4 "register-resident U":
//  - 256 blocks x 512 threads (1 block/CU, 8 waves).
//  - Phase A: block b<128 owns rows [8b,8b+8) of U_z; b>=128 same rows of U_r.
//    The 8x1024 slice lives in 128 VGPRs per lane (k = m*64+lane), staged ONCE.
//  - Phase C: block b owns rows [4b,4b+4) of U_h, staged ONCE into 16KB LDS.
//  - Per node: wave reads parent state coalesced into 16 regs, 128 reg-FMAs,
//    10-shuffle butterfly reduce (lane l ends with row l&7 sum), tiny epilogue.
//    No LDS staging, no per-node syncthreads, waves free-run between barriers.
//  => U global traffic 12MB once (was ~600MB redundant); B reads are the
//     unavoidable per-CU broadcast (~32MB/CU total, L2-served).
// ---------------------------------------------------------------------------
#define REC_GRID 256
#define GRPSH 4
#define GRP   (1<<GRPSH)            // 16 blocks per group
#define NGRP  (REC_GRID>>GRPSH)     // 16 groups

__device__ __forceinline__ void gbar(u32* bar){
  // layout (u32): bar[0]=gen | bar[16+g*16]=group g cnt | bar[16+NGRP*16]=root
  __syncthreads();
  if(threadIdx.x==0){
    __threadfence();
    u32* gen  = bar;
    u32* gcnt = bar + 16 + ((blockIdx.x>>GRPSH)<<4);
    u32* root = bar + 16 + (NGRP<<4);
    u32 g = __hip_atomic_load(gen, __ATOMIC_RELAXED, __HIP_MEMORY_SCOPE_AGENT);
    u32 a = __hip_atomic_fetch_add(gcnt, 1u, __ATOMIC_ACQ_REL, __HIP_MEMORY_SCOPE_AGENT);
    if(a == GRP-1u){
      __hip_atomic_store(gcnt, 0u, __ATOMIC_RELAXED, __HIP_MEMORY_SCOPE_AGENT);
      u32 b = __hip_atomic_fetch_add(root, 1u, __ATOMIC_ACQ_REL, __HIP_MEMORY_SCOPE_AGENT);
      if(b == NGRP-1u){
        __hip_atomic_store(root, 0u, __ATOMIC_RELAXED, __HIP_MEMORY_SCOPE_AGENT);
        __hip_atomic_fetch_add(gen, 1u, __ATOMIC_RELEASE, __HIP_MEMORY_SCOPE_AGENT);
      }
    }
    while(__hip_atomic_load(gen, __ATOMIC_ACQUIRE, __HIP_MEMORY_SCOPE_AGENT)==g){
      __builtin_amdgcn_s_sleep(8);
    }
    __threadfence();
  }
  __syncthreads();
}

// combine two accumulator slots a,b across lane stride s:
// lanes with (lane&s)==0 end with slot-a pair-sum, ==s with slot-b pair-sum.
__device__ __forceinline__ float comb(float a, float b, int s, int lane){
  const bool hi = (lane & s) != 0;
  float send = hi ? a : b;
  float sel  = hi ? b : a;
  return sel + __shfl_xor(send, s, 64);
}

__global__ __launch_bounds__(512,2) void k_rec(
    const int* __restrict__ parent,
    const float* __restrict__ Uz, const float* __restrict__ Ur, const float* __restrict__ Uh,
    float* __restrict__ wz, float* __restrict__ wr, float* __restrict__ wh,
    float* __restrict__ node_h,
    const int* __restrict__ meta, const int* __restrict__ lstart, const int* __restrict__ order,
    u32* __restrict__ bar){
  __shared__ float UhL[4*HID];     // 16 KB: this block's 4 rows of U_h
  const int t=threadIdx.x, lane=t&63, wv=t>>6;   // 8 waves
  const int b = blockIdx.x;
  const bool isZ = b < 128;
  const int roA = (b & 127) << 3;  // 8 rows (phase A)
  const int roC = b << 2;          // 4 rows (phase C)
  const int nlev = meta[0];

  // ---- one-time staging ----
  const float* UA = isZ ? Uz : Ur;
  float ua[8][16];
  #pragma unroll
  for(int r=0;r<8;r++)
    #pragma unroll
    for(int m=0;m<16;m++)
      ua[r][m] = UA[(size_t)(roA+r)*HID + (m<<6) + lane];
  for(int i=t;i<4*HID;i+=512) UhL[i] = Uh[(size_t)roC*HID + i];
  __syncthreads();

  for(int lev=0; lev<nlev; ++lev){
    const int s=lstart[lev], e=lstart[lev+1];
    const int L=e-s;
    // ---- phase A: z (b<128) or r (b>=128) for all nodes of the level ----
    for(int j=wv; j<L; j+=8){
      const int n = order[s+j];
      const int p = parent[n];
      const float* ph = node_h + (size_t)p*HID;
      float bb[16];
      #pragma unroll
      for(int m=0;m<16;m++) bb[m] = ph[(m<<6)+lane];
      float acc[8]={0.f,0.f,0.f,0.f,0.f,0.f,0.f,0.f};
      #pragma unroll
      for(int r=0;r<8;r++)
        #pragma unroll
        for(int m=0;m<16;m++)
          acc[r] = fmaf(ua[r][m], bb[m], acc[r]);
      // butterfly: lane l -> full sum of row (l&7)
      float c0=comb(acc[0],acc[1],1,lane), c1=comb(acc[2],acc[3],1,lane);
      float c2=comb(acc[4],acc[5],1,lane), c3=comb(acc[6],acc[7],1,lane);
      float d0=comb(c0,c1,2,lane), d1=comb(c2,c3,2,lane);
      float v=comb(d0,d1,4,lane);
      v += __shfl_xor(v,8,64); v += __shfl_xor(v,16,64); v += __shfl_xor(v,32,64);
      if(lane<8){
        const int row = roA + lane;
        const size_t idx = (size_t)n*HID + row;
        if(isZ){
          wz[idx] = sigmf(wz[idx] + v);
        }else{
          wr[idx] = sigmf(wr[idx] + v) * node_h[(size_t)p*HID + row];
        }
      }
    }
    gbar(bar);
    // ---- phase C: h-candidate + state update (4 rows per block) ----
    for(int j=wv; j<L; j+=8){
      const int n = order[s+j];
      const int p = parent[n];
      const float* bw = wr + (size_t)n*HID;
      float bb[16];
      #pragma unroll
      for(int m=0;m<16;m++) bb[m] = bw[(m<<6)+lane];
      float acc[4]={0.f,0.f,0.f,0.f};
      #pragma unroll
      for(int r=0;r<4;r++)
        #pragma unroll
        for(int m=0;m<16;m++)
          acc[r] = fmaf(UhL[(r<<10)+(m<<6)+lane], bb[m], acc[r]);
      float c0=comb(acc[0],acc[1],1,lane), c1=comb(acc[2],acc[3],1,lane);
      float v=comb(c0,c1,2,lane);
      v += __shfl_xor(v,4,64); v += __shfl_xor(v,8,64);
      v += __shfl_xor(v,16,64); v += __shfl_xor(v,32,64);
      if(lane<4){
        const int row = roC + lane;
        const size_t idx = (size_t)n*HID + row;
        const float z  = wz[idx];                       // sigmoided in phase A
        const float pv = node_h[(size_t)p*HID + row];
        const float c  = tanhf(wh[idx] + v);
        node_h[(size_t)(n+1)*HID + row] = z*pv + (1.f-z)*c;
      }
    }
    gbar(bar);
  }
}

// ---------------------------------------------------------------------------
// Leaf max + softmax + loss. Output: FP32 pred[4], loss.
// ---------------------------------------------------------------------------
__global__ __launch_bounds__(1024) void k_final(const float* __restrict__ node_h,
                                                const int* __restrict__ leaf,
                                                const float* __restrict__ Wout,
                                                const float* __restrict__ bout,
                                                const float* __restrict__ y,
                                                float* __restrict__ out){
  __shared__ int li[NLEAVES];
  __shared__ float fs[HID];
  __shared__ float logits[NCLASS];
  const int t=threadIdx.x;
  li[t]=leaf[t];
  __syncthreads();
  float m=-INFINITY;
  for(int l=0;l<NLEAVES;l++) m = fmaxf(m, node_h[(size_t)li[l]*HID + t]);
  fs[t]=m;
  __syncthreads();
  const int wave=t>>6, lane=t&63;
  if(wave<NCLASS){
    float p=0.f;
    for(int h=lane;h<HID;h+=64) p += Wout[wave*HID+h]*fs[h];
    for(int off=32; off; off>>=1) p += __shfl_down(p, off);
    if(lane==0) logits[wave]=p+bout[wave];
  }
  __syncthreads();
  if(t==0){
    float mx = fmaxf(fmaxf(logits[0],logits[1]),fmaxf(logits[2],logits[3]));
    float ev[NCLASS]; float es=0.f;
    #pragma unroll
    for(int c=0;c<NCLASS;c++){ ev[c]=expf(logits[c]-mx); es+=ev[c]; }
    float loss=0.f;
    #pragma unroll
    for(int c=0;c<NCLASS;c++){
      float p=ev[c]/es;
      out[c]=p;
      float d=y[c]-p; loss+=d*d;
    }
    out[NCLASS]=loss;
  }
}

// ---------------------------------------------------------------------------
extern "C" void kernel_launch(void* const* d_in, const int* in_sizes, int n_in,
                              void* d_out, int out_size, void* d_ws, size_t ws_size,
                              hipStream_t stream){
  (void)in_sizes; (void)n_in; (void)out_size;
  const float* x_word=(const float*)d_in[0];
  const int*   x_index=(const int*)d_in[1];
  const int*   parent =(const int*)d_in[2];
  const int*   leaf   =(const int*)d_in[3];
  const float* y      =(const float*)d_in[4];
  const float* E      =(const float*)d_in[5];
  const float* W_z=(const float*)d_in[6];  const float* U_z=(const float*)d_in[7];  const float* b_z=(const float*)d_in[8];
  const float* W_r=(const float*)d_in[9];  const float* U_r=(const float*)d_in[10]; const float* b_r=(const float*)d_in[11];
  const float* W_h=(const float*)d_in[12]; const float* U_h=(const float*)d_in[13]; const float* b_h=(const float*)d_in[14];
  const float* W_out=(const float*)d_in[15]; const float* b_out=(const float*)d_in[16];

  size_t off=0;
  char* wsb=(char*)d_ws;
  auto alloc=[&](size_t b)->void*{ void* p=wsb+off; off=(off+b+255)&~(size_t)255; return p; };
  u32*  bar    = (u32*)  alloc(4096);
  int*  meta   = (int*)  alloc(256);
  int*  lstart = (int*)  alloc((N_NODES+1)*sizeof(int));
  int*  order  = (int*)  alloc(N_NODES*sizeof(int));
  float* node_h= (float*)alloc((size_t)(N_NODES+1)*HID*sizeof(float));
  float* xe    = (float*)alloc((size_t)N_NODES*HID*sizeof(float));
  float* wz    = (float*)alloc((size_t)N_NODES*HID*sizeof(float));
  float* wr    = (float*)alloc((size_t)N_NODES*HID*sizeof(float));
  float* wh    = (float*)alloc((size_t)N_NODES*HID*sizeof(float));
  float* ET    = (float*)(wsb+off);
  const size_t need_ET = off + (size_t)VOCAB*HID*sizeof(float);
  const bool useET = (ws_size >= need_ET);

  hipMemsetAsync(bar, 0, 4096, stream);
  k_levels<<<1,1024,0,stream>>>(parent, meta, lstart, order, node_h);
  if(useET){
    k_transpose<<<dim3((VOCAB+31)/32, HID/32),256,0,stream>>>(E, ET);
    k_xe<<<N_NODES,256,0,stream>>>(ET, x_word, x_index, xe);
  }else{
    k_xe_noET<<<N_NODES,256,0,stream>>>(E, x_word, x_index, xe);
  }
  k_gemm_in<<<dim3(N_NODES/64, HID/64, 3),256,0,stream>>>(xe, W_z,W_r,W_h, b_z,b_r,b_h, wz,wr,wh);
  k_rec<<<REC_GRID,512,0,stream>>>(parent, U_z,U_r,U_h, wz,wr,wh, node_h, meta, lstart, order, bar);
  k_final<<<1,1024,0,stream>>>(node_h, leaf, W_out, b_out, y, (float*)d_out);
}

// Round 8
// 2719.621 us; speedup vs baseline: 2.1771x; 1.0947x over previous
//
#include <hip/hip_runtime.h>
#include <hip/hip_bf16.h>
#include <math.h>

#define N_NODES 4096
#define WPN 32
#define HID 1024
#define VOCAB 30000
#define NCLASS 4
#define NLEAVES 1024

typedef unsigned int u32;
typedef unsigned short u16;

__device__ __forceinline__ float sigmf(float x){ return 1.f/(1.f+expf(-x)); }

// ---------------------------------------------------------------------------
// Level schedule: depth[i] via iterative relaxation in LDS, then counting sort.
// Also zeroes node_h row 0 (root parent).
// ---------------------------------------------------------------------------
__global__ __launch_bounds__(1024) void k_levels(const int* __restrict__ parent,
                                                 int* __restrict__ meta,
                                                 int* __restrict__ lstart,
                                                 int* __restrict__ order,
                                                 float* __restrict__ node_h){
  __shared__ int dep[N_NODES];
  __shared__ int dpt[N_NODES];
  __shared__ int cnt[N_NODES];
  __shared__ int changed, maxd;
  const int t = threadIdx.x;
  for(int i=t;i<N_NODES;i+=1024){ dep[i]=parent[i]-1; dpt[i]=0; cnt[i]=0; }
  if(t==0){ maxd=0; }
  node_h[t]=0.f;  // 1024 threads == HID: zero root-parent row
  __syncthreads();
  while(true){
    if(t==0) changed=0;
    __syncthreads();
    bool ch=false;
    for(int i=t;i<N_NODES;i+=1024){
      int d = (dep[i]<0)? 0 : (dpt[dep[i]]+1);
      if(d>dpt[i]){ dpt[i]=d; ch=true; }
    }
    if(ch) changed=1;
    __syncthreads();
    if(!changed) break;
    __syncthreads();
  }
  __syncthreads();
  for(int i=t;i<N_NODES;i+=1024){ atomicAdd(&cnt[dpt[i]],1); atomicMax(&maxd,dpt[i]); }
  __syncthreads();
  // inclusive scan of cnt -> sc (reuse dep)
  int* sc = dep;
  for(int i=t;i<N_NODES;i+=1024) sc[i]=cnt[i];
  __syncthreads();
  for(int off=1; off<N_NODES; off<<=1){
    int v[4];
    #pragma unroll
    for(int u=0;u<4;u++){ int i=t+u*1024; v[u] = (i>=off)? sc[i-off] : 0; }
    __syncthreads();
    #pragma unroll
    for(int u=0;u<4;u++){ int i=t+u*1024; sc[i]+=v[u]; }
    __syncthreads();
  }
  for(int i=t;i<N_NODES;i+=1024) lstart[i+1]=sc[i];
  if(t==0){ lstart[0]=0; meta[0]=maxd+1; }
  // exclusive starts into cnt for scatter
  for(int i=t;i<N_NODES;i+=1024) cnt[i]=sc[i]-cnt[i];
  __syncthreads();
  for(int i=t;i<N_NODES;i+=1024){
    int pos = atomicAdd(&cnt[dpt[i]],1);
    order[pos]=i;
  }
}

// ---------------------------------------------------------------------------
// E [HID][VOCAB] f32  ->  ET [VOCAB][HID] f32  (tiled transpose)
// ---------------------------------------------------------------------------
__global__ __launch_bounds__(256) void k_transpose(const float* __restrict__ E,
                                                   float* __restrict__ ET){
  __shared__ float tile[32][33];
  const int v0 = blockIdx.x*32, h0 = blockIdx.y*32;
  const int tx = threadIdx.x%32, ty = threadIdx.x/32;   // ty 0..7
  #pragma unroll
  for(int i=0;i<4;i++){
    int h = h0+ty+8*i, v = v0+tx;
    tile[ty+8*i][tx] = (v<VOCAB)? E[(size_t)h*VOCAB + v] : 0.f;
  }
  __syncthreads();
  #pragma unroll
  for(int i=0;i<4;i++){
    int v = v0+ty+8*i, h = h0+tx;
    if(v<VOCAB) ET[(size_t)v*HID + h] = tile[tx][ty+8*i];
  }
}

// ---------------------------------------------------------------------------
// xe[n,h] = sum_l w[n,l] * ET[idx[n,l], h]   (one block per node, coalesced)
// ---------------------------------------------------------------------------
__global__ __launch_bounds__(256) void k_xe(const float* __restrict__ ET,
                                            const float* __restrict__ xw,
                                            const int* __restrict__ xi,
                                            float* __restrict__ xe){
  const int n = blockIdx.x;
  __shared__ float w[WPN]; __shared__ int id[WPN];
  const int t = threadIdx.x;
  if(t<WPN){ w[t]=xw[n*WPN+t]; id[t]=xi[n*WPN+t]; }
  __syncthreads();
  const int h0 = t*4;
  float a0=0,a1=0,a2=0,a3=0;
  for(int l=0;l<WPN;l++){
    const float4 e = *(const float4*)(ET + (size_t)id[l]*HID + h0);
    const float wl = w[l];
    a0 += wl*e.x; a1 += wl*e.y; a2 += wl*e.z; a3 += wl*e.w;
  }
  *(float4*)(xe + (size_t)n*HID + h0) = make_float4(a0,a1,a2,a3);
}

// Fallback when ws too small for fp32 ET: direct strided gather from E.
__global__ __launch_bounds__(256) void k_xe_noET(const float* __restrict__ E,
                                                 const float* __restrict__ xw,
                                                 const int* __restrict__ xi,
                                                 float* __restrict__ xe){
  const int n = blockIdx.x;
  __shared__ float w[WPN]; __shared__ int id[WPN];
  const int t = threadIdx.x;
  if(t<WPN){ w[t]=xw[n*WPN+t]; id[t]=xi[n*WPN+t]; }
  __syncthreads();
  const int h0 = t*4;
  float acc[4]={0,0,0,0};
  for(int l=0;l<WPN;l++){
    const float wl=w[l]; const int ix=id[l];
    #pragma unroll
    for(int j=0;j<4;j++) acc[j] += wl*E[(size_t)(h0+j)*VOCAB + ix];
  }
  *(float4*)(xe + (size_t)n*HID + h0) = make_float4(acc[0],acc[1],acc[2],acc[3]);
}

// ---------------------------------------------------------------------------
// Input-side projections: out_g[n,o] = b_g[o] + sum_k xe[n,k]*W_g[o,k]
// 64x64 tile, BK=32, k-major LDS, 4x4 micro-tile.
// ---------------------------------------------------------------------------
__global__ __launch_bounds__(256) void k_gemm_in(const float* __restrict__ xe,
  const float* __restrict__ W0,const float* __restrict__ W1,const float* __restrict__ W2,
  const float* __restrict__ b0,const float* __restrict__ b1,const float* __restrict__ b2,
  float* __restrict__ o0p,float* __restrict__ o1p,float* __restrict__ o2p){
  __shared__ float A[32*68];
  __shared__ float B[32*68];
  const int g=blockIdx.z;
  const float* W  = (g==0)?W0:((g==1)?W1:W2);
  const float* bi = (g==0)?b0:((g==1)?b1:b2);
  float* out      = (g==0)?o0p:((g==1)?o1p:o2p);
  const int n0=blockIdx.x<<6, q0=blockIdx.y<<6;
  const int t=threadIdx.x, tx=t&15, ty=t>>4;
  float acc[4][4]={};
  for(int k0=0;k0<HID;k0+=32){
    #pragma unroll
    for(int m=0;m<2;m++){
      int idx=t+(m<<8); int r=idx>>3; int c4=(idx&7)<<2;
      float4 v=*(const float4*)(xe+(size_t)(n0+r)*HID+k0+c4);
      A[(c4+0)*68+r]=v.x; A[(c4+1)*68+r]=v.y; A[(c4+2)*68+r]=v.z; A[(c4+3)*68+r]=v.w;
      float4 u=*(const float4*)(W+(size_t)(q0+r)*HID+k0+c4);
      B[(c4+0)*68+r]=u.x; B[(c4+1)*68+r]=u.y; B[(c4+2)*68+r]=u.z; B[(c4+3)*68+r]=u.w;
    }
    __syncthreads();
    #pragma unroll 8
    for(int k=0;k<32;k++){
      const float4 a=*(const float4*)&A[k*68+(ty<<2)];
      const float4 b=*(const float4*)&B[k*68+(tx<<2)];
      acc[0][0]+=a.x*b.x; acc[0][1]+=a.x*b.y; acc[0][2]+=a.x*b.z; acc[0][3]+=a.x*b.w;
      acc[1][0]+=a.y*b.x; acc[1][1]+=a.y*b.y; acc[1][2]+=a.y*b.z; acc[1][3]+=a.y*b.w;
      acc[2][0]+=a.z*b.x; acc[2][1]+=a.z*b.y; acc[2][2]+=a.z*b.z; acc[2][3]+=a.z*b.w;
      acc[3][0]+=a.w*b.x; acc[3][1]+=a.w*b.y; acc[3][2]+=a.w*b.z; acc[3][3]+=a.w*b.w;
    }
    __syncthreads();
  }
  const float4 bb=*(const float4*)(bi+q0+(tx<<2));
  #pragma unroll
  for(int i=0;i<4;i++){
    const int n=n0+(ty<<2)+i;
    float4 r4 = make_float4(acc[i][0]+bb.x, acc[i][1]+bb.y, acc[i][2]+bb.z, acc[i][3]+bb.w);
    *(float4*)(out+(size_t)n*HID+q0+(tx<<2)) = r4;
  }
}

// ---------------------------------------------------------------------------
// Persistent level-synchronous recurrence, v6 "XCD-local fan-out, 1 block/CU":
//  Round-7 deadlock root cause: __launch_bounds__(512,2) = 2 waves/EU = 8
//  waves/CU = only 1 block/CU guaranteed, but the grid was 512 (needed 2/CU)
//  -> half the blocks never resident -> grid barrier spins forever.
//  v6: 256 blocks (1/CU, co-residency guaranteed: LDS=0, VGPR<=256 via
//  launch_bounds), keep XCD-locality:
//   - group g = blockIdx&7 (~XCD via RR dispatch); nodes j==g (mod 8).
//   - 32 blocks/group. Phase A: blocks i<16 own z, i>=16 own r; each wave
//     holds 8 DISTINCT rows in ua[8][16] (128 VGPR) -> 64 rows/block.
//   - Phase C: each wave holds 4 rows of U_h in uh[4][16] (64 VGPR)
//     -> 32 rows/block. No LDS, no re-reads of U ever (register-resident,
//     immune to the fence-driven L2 invalidation seen as ~318MB FETCH).
//   - Per node: only ONE XCD touches the 4KB parent vector; phase C's wr[n]
//     read is same-XCD L2-local (written there in phase A).
// ---------------------------------------------------------------------------
#define REC_GRID 256
#define GRPSH 4
#define GRP   (1<<GRPSH)            // 16 blocks per barrier-group
#define NGRP  (REC_GRID>>GRPSH)     // 16 groups

__device__ __forceinline__ void gbar(u32* bar){
  // layout (u32): bar[0]=gen | bar[16+g*16]=group g cnt | bar[16+NGRP*16]=root
  __syncthreads();
  if(threadIdx.x==0){
    __threadfence();
    u32* gen  = bar;
    u32* gcnt = bar + 16 + ((blockIdx.x>>GRPSH)<<4);
    u32* root = bar + 16 + (NGRP<<4);
    u32 g = __hip_atomic_load(gen, __ATOMIC_RELAXED, __HIP_MEMORY_SCOPE_AGENT);
    u32 a = __hip_atomic_fetch_add(gcnt, 1u, __ATOMIC_ACQ_REL, __HIP_MEMORY_SCOPE_AGENT);
    if(a == GRP-1u){
      __hip_atomic_store(gcnt, 0u, __ATOMIC_RELAXED, __HIP_MEMORY_SCOPE_AGENT);
      u32 b = __hip_atomic_fetch_add(root, 1u, __ATOMIC_ACQ_REL, __HIP_MEMORY_SCOPE_AGENT);
      if(b == NGRP-1u){
        __hip_atomic_store(root, 0u, __ATOMIC_RELAXED, __HIP_MEMORY_SCOPE_AGENT);
        __hip_atomic_fetch_add(gen, 1u, __ATOMIC_RELEASE, __HIP_MEMORY_SCOPE_AGENT);
      }
    }
    while(__hip_atomic_load(gen, __ATOMIC_ACQUIRE, __HIP_MEMORY_SCOPE_AGENT)==g){
      __builtin_amdgcn_s_sleep(8);
    }
    __threadfence();
  }
  __syncthreads();
}

// combine two accumulator slots a,b across lane stride s:
// lanes with (lane&s)==0 end with slot-a pair-sum, ==s with slot-b pair-sum.
__device__ __forceinline__ float comb(float a, float b, int s, int lane){
  const bool hi = (lane & s) != 0;
  float send = hi ? a : b;
  float sel  = hi ? b : a;
  return sel + __shfl_xor(send, s, 64);
}

__global__ __launch_bounds__(512,2) void k_rec(
    const int* __restrict__ parent,
    const float* __restrict__ Uz, const float* __restrict__ Ur, const float* __restrict__ Uh,
    float* __restrict__ wz, float* __restrict__ wr, float* __restrict__ wh,
    float* __restrict__ node_h,
    const int* __restrict__ meta, const int* __restrict__ lstart, const int* __restrict__ order,
    u32* __restrict__ bar){
  const int t=threadIdx.x, lane=t&63, wv=t>>6;   // 8 waves
  const int g = blockIdx.x & 7;      // node group (~XCD)
  const int i = blockIdx.x >> 3;     // 0..31 within group
  const bool isZ = i < 16;
  const int rA = ((i&15)<<6) + (wv<<3);  // phase A: 8 rows per wave
  const int rC = (i<<5) + (wv<<2);       // phase C: 4 rows per wave
  const int nlev = meta[0];

  // ---- one-time staging (all register-resident, statically indexed) ----
  const float* UA = isZ ? Uz : Ur;
  float ua[8][16];
  #pragma unroll
  for(int r=0;r<8;r++)
    #pragma unroll
    for(int m=0;m<16;m++)
      ua[r][m] = UA[(size_t)(rA+r)*HID + (m<<6) + lane];
  float uh[4][16];
  #pragma unroll
  for(int r=0;r<4;r++)
    #pragma unroll
    for(int m=0;m<16;m++)
      uh[r][m] = Uh[(size_t)(rC+r)*HID + (m<<6) + lane];

  for(int lev=0; lev<nlev; ++lev){
    const int s=lstart[lev];
    const int L=lstart[lev+1]-s;
    // ---- phase A: z (i<16) or r (i>=16) rows for this group's nodes ----
    for(int jj=g; jj<L; jj+=8){
      const int n = order[s+jj];
      const int p = parent[n];
      const float* ph = node_h + (size_t)p*HID;
      float bb[16];
      #pragma unroll
      for(int m=0;m<16;m++) bb[m]=ph[(m<<6)+lane];
      float a0=0.f,a1=0.f,a2=0.f,a3=0.f,a4=0.f,a5=0.f,a6=0.f,a7=0.f;
      #pragma unroll
      for(int m=0;m<16;m++){
        const float b=bb[m];
        a0=fmaf(ua[0][m],b,a0); a1=fmaf(ua[1][m],b,a1);
        a2=fmaf(ua[2][m],b,a2); a3=fmaf(ua[3][m],b,a3);
        a4=fmaf(ua[4][m],b,a4); a5=fmaf(ua[5][m],b,a5);
        a6=fmaf(ua[6][m],b,a6); a7=fmaf(ua[7][m],b,a7);
      }
      float c0=comb(a0,a1,1,lane), c1=comb(a2,a3,1,lane);
      float c2=comb(a4,a5,1,lane), c3=comb(a6,a7,1,lane);
      float d0=comb(c0,c1,2,lane), d1=comb(c2,c3,2,lane);
      float v=comb(d0,d1,4,lane);
      v+=__shfl_xor(v,8,64); v+=__shfl_xor(v,16,64); v+=__shfl_xor(v,32,64);
      if(lane<8){
        const int row=rA+lane;
        const size_t idx=(size_t)n*HID+row;
        if(isZ) wz[idx]=sigmf(wz[idx]+v);
        else    wr[idx]=sigmf(wr[idx]+v)*node_h[(size_t)p*HID+row];
      }
    }
    gbar(bar);
    // ---- phase C: h-candidate + state update (4 rows per wave) ----
    for(int jj=g; jj<L; jj+=8){
      const int n = order[s+jj];
      const int p = parent[n];
      const float* bw = wr + (size_t)n*HID;
      float bb[16];
      #pragma unroll
      for(int m=0;m<16;m++) bb[m]=bw[(m<<6)+lane];
      float a0=0.f,a1=0.f,a2=0.f,a3=0.f;
      #pragma unroll
      for(int m=0;m<16;m++){
        const float b=bb[m];
        a0=fmaf(uh[0][m],b,a0); a1=fmaf(uh[1][m],b,a1);
        a2=fmaf(uh[2][m],b,a2); a3=fmaf(uh[3][m],b,a3);
      }
      float c0=comb(a0,a1,1,lane), c1=comb(a2,a3,1,lane);
      float v=comb(c0,c1,2,lane);
      v+=__shfl_xor(v,4,64); v+=__shfl_xor(v,8,64);
      v+=__shfl_xor(v,16,64); v+=__shfl_xor(v,32,64);
      if(lane<4){
        const int row=rC+lane;
        const size_t idx=(size_t)n*HID+row;
        const float z=wz[idx];                      // sigmoided in phase A
        const float pv=node_h[(size_t)p*HID+row];
        const float c=tanhf(wh[idx]+v);
        node_h[(size_t)(n+1)*HID+row]=z*pv+(1.f-z)*c;
      }
    }
    gbar(bar);
  }
}

// ---------------------------------------------------------------------------
// Leaf max + softmax + loss. Output: FP32 pred[4], loss.
// ---------------------------------------------------------------------------
__global__ __launch_bounds__(1024) void k_final(const float* __restrict__ node_h,
                                                const int* __restrict__ leaf,
                                                const float* __restrict__ Wout,
                                                const float* __restrict__ bout,
                                                const float* __restrict__ y,
                                                float* __restrict__ out){
  __shared__ int li[NLEAVES];
  __shared__ float fs[HID];
  __shared__ float logits[NCLASS];
  const int t=threadIdx.x;
  li[t]=leaf[t];
  __syncthreads();
  float m=-INFINITY;
  for(int l=0;l<NLEAVES;l++) m = fmaxf(m, node_h[(size_t)li[l]*HID + t]);
  fs[t]=m;
  __syncthreads();
  const int wave=t>>6, lane=t&63;
  if(wave<NCLASS){
    float p=0.f;
    for(int h=lane;h<HID;h+=64) p += Wout[wave*HID+h]*fs[h];
    for(int off=32; off; off>>=1) p += __shfl_down(p, off);
    if(lane==0) logits[wave]=p+bout[wave];
  }
  __syncthreads();
  if(t==0){
    float mx = fmaxf(fmaxf(logits[0],logits[1]),fmaxf(logits[2],logits[3]));
    float ev[NCLASS]; float es=0.f;
    #pragma unroll
    for(int c=0;c<NCLASS;c++){ ev[c]=expf(logits[c]-mx); es+=ev[c]; }
    float loss=0.f;
    #pragma unroll
    for(int c=0;c<NCLASS;c++){
      float p=ev[c]/es;
      out[c]=p;
      float d=y[c]-p; loss+=d*d;
    }
    out[NCLASS]=loss;
  }
}

// ---------------------------------------------------------------------------
extern "C" void kernel_launch(void* const* d_in, const int* in_sizes, int n_in,
                              void* d_out, int out_size, void* d_ws, size_t ws_size,
                              hipStream_t stream){
  (void)in_sizes; (void)n_in; (void)out_size;
  const float* x_word=(const float*)d_in[0];
  const int*   x_index=(const int*)d_in[1];
  const int*   parent =(const int*)d_in[2];
  const int*   leaf   =(const int*)d_in[3];
  const float* y      =(const float*)d_in[4];
  const float* E      =(const float*)d_in[5];
  const float* W_z=(const float*)d_in[6];  const float* U_z=(const float*)d_in[7];  const float* b_z=(const float*)d_in[8];
  const float* W_r=(const float*)d_in[9];  const float* U_r=(const float*)d_in[10]; const float* b_r=(const float*)d_in[11];
  const float* W_h=(const float*)d_in[12]; const float* U_h=(const float*)d_in[13]; const float* b_h=(const float*)d_in[14];
  const float* W_out=(const float*)d_in[15]; const float* b_out=(const float*)d_in[16];

  size_t off=0;
  char* wsb=(char*)d_ws;
  auto alloc=[&](size_t b)->void*{ void* p=wsb+off; off=(off+b+255)&~(size_t)255; return p; };
  u32*  bar    = (u32*)  alloc(4096);
  int*  meta   = (int*)  alloc(256);
  int*  lstart = (int*)  alloc((N_NODES+1)*sizeof(int));
  int*  order  = (int*)  alloc(N_NODES*sizeof(int));
  float* node_h= (float*)alloc((size_t)(N_NODES+1)*HID*sizeof(float));
  float* xe    = (float*)alloc((size_t)N_NODES*HID*sizeof(float));
  float* wz    = (float*)alloc((size_t)N_NODES*HID*sizeof(float));
  float* wr    = (float*)alloc((size_t)N_NODES*HID*sizeof(float));
  float* wh    = (float*)alloc((size_t)N_NODES*HID*sizeof(float));
  float* ET    = (float*)(wsb+off);
  const size_t need_ET = off + (size_t)VOCAB*HID*sizeof(float);
  const bool useET = (ws_size >= need_ET);

  hipMemsetAsync(bar, 0, 4096, stream);
  k_levels<<<1,1024,0,stream>>>(parent, meta, lstart, order, node_h);
  if(useET){
    k_transpose<<<dim3((VOCAB+31)/32, HID/32),256,0,stream>>>(E, ET);
    k_xe<<<N_NODES,256,0,stream>>>(ET, x_word, x_index, xe);
  }else{
    k_xe_noET<<<N_NODES,256,0,stream>>>(E, x_word, x_index, xe);
  }
  k_gemm_in<<<dim3(N_NODES/64, HID/64, 3),256,0,stream>>>(xe, W_z,W_r,W_h, b_z,b_r,b_h, wz,wr,wh);
  k_rec<<<REC_GRID,512,0,stream>>>(parent, U_z,U_r,U_h, wz,wr,wh, node_h, meta, lstart, order, bar);
  k_final<<<1,1024,0,stream>>>(node_h, leaf, W_out, b_out, y, (float*)d_out);
}

// Round 9
// 2567.132 us; speedup vs baseline: 2.3064x; 1.0594x over previous
//
#include <hip/hip_runtime.h>
#include <hip/hip_bf16.h>
#include <math.h>

#define N_NODES 4096
#define WPN 32
#define HID 1024
#define VOCAB 30000
#define NCLASS 4
#define NLEAVES 1024

typedef unsigned int u32;
typedef unsigned short u16;

__device__ __forceinline__ float sigmf(float x){ return 1.f/(1.f+expf(-x)); }

// ---------------------------------------------------------------------------
// Level schedule: depth[i] via iterative relaxation in LDS, then counting sort.
// Also zeroes node_h row 0 (root parent).
// ---------------------------------------------------------------------------
__global__ __launch_bounds__(1024) void k_levels(const int* __restrict__ parent,
                                                 int* __restrict__ meta,
                                                 int* __restrict__ lstart,
                                                 int* __restrict__ order,
                                                 float* __restrict__ node_h){
  __shared__ int dep[N_NODES];
  __shared__ int dpt[N_NODES];
  __shared__ int cnt[N_NODES];
  __shared__ int changed, maxd;
  const int t = threadIdx.x;
  for(int i=t;i<N_NODES;i+=1024){ dep[i]=parent[i]-1; dpt[i]=0; cnt[i]=0; }
  if(t==0){ maxd=0; }
  node_h[t]=0.f;  // 1024 threads == HID: zero root-parent row
  __syncthreads();
  while(true){
    if(t==0) changed=0;
    __syncthreads();
    bool ch=false;
    for(int i=t;i<N_NODES;i+=1024){
      int d = (dep[i]<0)? 0 : (dpt[dep[i]]+1);
      if(d>dpt[i]){ dpt[i]=d; ch=true; }
    }
    if(ch) changed=1;
    __syncthreads();
    if(!changed) break;
    __syncthreads();
  }
  __syncthreads();
  for(int i=t;i<N_NODES;i+=1024){ atomicAdd(&cnt[dpt[i]],1); atomicMax(&maxd,dpt[i]); }
  __syncthreads();
  // inclusive scan of cnt -> sc (reuse dep)
  int* sc = dep;
  for(int i=t;i<N_NODES;i+=1024) sc[i]=cnt[i];
  __syncthreads();
  for(int off=1; off<N_NODES; off<<=1){
    int v[4];
    #pragma unroll
    for(int u=0;u<4;u++){ int i=t+u*1024; v[u] = (i>=off)? sc[i-off] : 0; }
    __syncthreads();
    #pragma unroll
    for(int u=0;u<4;u++){ int i=t+u*1024; sc[i]+=v[u]; }
    __syncthreads();
  }
  for(int i=t;i<N_NODES;i+=1024) lstart[i+1]=sc[i];
  if(t==0){ lstart[0]=0; meta[0]=maxd+1; }
  // exclusive starts into cnt for scatter
  for(int i=t;i<N_NODES;i+=1024) cnt[i]=sc[i]-cnt[i];
  __syncthreads();
  for(int i=t;i<N_NODES;i+=1024){
    int pos = atomicAdd(&cnt[dpt[i]],1);
    order[pos]=i;
  }
}

// ---------------------------------------------------------------------------
// E [HID][VOCAB] f32  ->  ET [VOCAB][HID] f32  (tiled transpose)
// ---------------------------------------------------------------------------
__global__ __launch_bounds__(256) void k_transpose(const float* __restrict__ E,
                                                   float* __restrict__ ET){
  __shared__ float tile[32][33];
  const int v0 = blockIdx.x*32, h0 = blockIdx.y*32;
  const int tx = threadIdx.x%32, ty = threadIdx.x/32;   // ty 0..7
  #pragma unroll
  for(int i=0;i<4;i++){
    int h = h0+ty+8*i, v = v0+tx;
    tile[ty+8*i][tx] = (v<VOCAB)? E[(size_t)h*VOCAB + v] : 0.f;
  }
  __syncthreads();
  #pragma unroll
  for(int i=0;i<4;i++){
    int v = v0+ty+8*i, h = h0+tx;
    if(v<VOCAB) ET[(size_t)v*HID + h] = tile[tx][ty+8*i];
  }
}

// ---------------------------------------------------------------------------
// xe[n,h] = sum_l w[n,l] * ET[idx[n,l], h]   (one block per node, coalesced)
// ---------------------------------------------------------------------------
__global__ __launch_bounds__(256) void k_xe(const float* __restrict__ ET,
                                            const float* __restrict__ xw,
                                            const int* __restrict__ xi,
                                            float* __restrict__ xe){
  const int n = blockIdx.x;
  __shared__ float w[WPN]; __shared__ int id[WPN];
  const int t = threadIdx.x;
  if(t<WPN){ w[t]=xw[n*WPN+t]; id[t]=xi[n*WPN+t]; }
  __syncthreads();
  const int h0 = t*4;
  float a0=0,a1=0,a2=0,a3=0;
  for(int l=0;l<WPN;l++){
    const float4 e = *(const float4*)(ET + (size_t)id[l]*HID + h0);
    const float wl = w[l];
    a0 += wl*e.x; a1 += wl*e.y; a2 += wl*e.z; a3 += wl*e.w;
  }
  *(float4*)(xe + (size_t)n*HID + h0) = make_float4(a0,a1,a2,a3);
}

// Fallback when ws too small for fp32 ET: direct strided gather from E.
__global__ __launch_bounds__(256) void k_xe_noET(const float* __restrict__ E,
                                                 const float* __restrict__ xw,
                                                 const int* __restrict__ xi,
                                                 float* __restrict__ xe){
  const int n = blockIdx.x;
  __shared__ float w[WPN]; __shared__ int id[WPN];
  const int t = threadIdx.x;
  if(t<WPN){ w[t]=xw[n*WPN+t]; id[t]=xi[n*WPN+t]; }
  __syncthreads();
  const int h0 = t*4;
  float acc[4]={0,0,0,0};
  for(int l=0;l<WPN;l++){
    const float wl=w[l]; const int ix=id[l];
    #pragma unroll
    for(int j=0;j<4;j++) acc[j] += wl*E[(size_t)(h0+j)*VOCAB + ix];
  }
  *(float4*)(xe + (size_t)n*HID + h0) = make_float4(acc[0],acc[1],acc[2],acc[3]);
}

// ---------------------------------------------------------------------------
// Input-side projections: out_g[n,o] = b_g[o] + sum_k xe[n,k]*W_g[o,k]
// 64x64 tile, BK=32, k-major LDS, 4x4 micro-tile.
// ---------------------------------------------------------------------------
__global__ __launch_bounds__(256) void k_gemm_in(const float* __restrict__ xe,
  const float* __restrict__ W0,const float* __restrict__ W1,const float* __restrict__ W2,
  const float* __restrict__ b0,const float* __restrict__ b1,const float* __restrict__ b2,
  float* __restrict__ o0p,float* __restrict__ o1p,float* __restrict__ o2p){
  __shared__ float A[32*68];
  __shared__ float B[32*68];
  const int g=blockIdx.z;
  const float* W  = (g==0)?W0:((g==1)?W1:W2);
  const float* bi = (g==0)?b0:((g==1)?b1:b2);
  float* out      = (g==0)?o0p:((g==1)?o1p:o2p);
  const int n0=blockIdx.x<<6, q0=blockIdx.y<<6;
  const int t=threadIdx.x, tx=t&15, ty=t>>4;
  float acc[4][4]={};
  for(int k0=0;k0<HID;k0+=32){
    #pragma unroll
    for(int m=0;m<2;m++){
      int idx=t+(m<<8); int r=idx>>3; int c4=(idx&7)<<2;
      float4 v=*(const float4*)(xe+(size_t)(n0+r)*HID+k0+c4);
      A[(c4+0)*68+r]=v.x; A[(c4+1)*68+r]=v.y; A[(c4+2)*68+r]=v.z; A[(c4+3)*68+r]=v.w;
      float4 u=*(const float4*)(W+(size_t)(q0+r)*HID+k0+c4);
      B[(c4+0)*68+r]=u.x; B[(c4+1)*68+r]=u.y; B[(c4+2)*68+r]=u.z; B[(c4+3)*68+r]=u.w;
    }
    __syncthreads();
    #pragma unroll 8
    for(int k=0;k<32;k++){
      const float4 a=*(const float4*)&A[k*68+(ty<<2)];
      const float4 b=*(const float4*)&B[k*68+(tx<<2)];
      acc[0][0]+=a.x*b.x; acc[0][1]+=a.x*b.y; acc[0][2]+=a.x*b.z; acc[0][3]+=a.x*b.w;
      acc[1][0]+=a.y*b.x; acc[1][1]+=a.y*b.y; acc[1][2]+=a.y*b.z; acc[1][3]+=a.y*b.w;
      acc[2][0]+=a.z*b.x; acc[2][1]+=a.z*b.y; acc[2][2]+=a.z*b.z; acc[2][3]+=a.z*b.w;
      acc[3][0]+=a.w*b.x; acc[3][1]+=a.w*b.y; acc[3][2]+=a.w*b.z; acc[3][3]+=a.w*b.w;
    }
    __syncthreads();
  }
  const float4 bb=*(const float4*)(bi+q0+(tx<<2));
  #pragma unroll
  for(int i=0;i<4;i++){
    const int n=n0+(ty<<2)+i;
    float4 r4 = make_float4(acc[i][0]+bb.x, acc[i][1]+bb.y, acc[i][2]+bb.z, acc[i][3]+bb.w);
    *(float4*)(out+(size_t)n*HID+q0+(tx<<2)) = r4;
  }
}

// ---------------------------------------------------------------------------
// Persistent level-synchronous recurrence, v7 "pinned register-resident U":
//  Round-8 counters: VGPR_Count=116 < the 192 floats/lane my ua+uh need =>
//  the compiler REMATERIALIZED the U loads inside the node loop (legal for
//  const-restrict), re-streaming ~6GB/XCD from L2 => the 2ms floor.
//  v7: (1) asm volatile("" : "+v") pin on every staged U element makes the
//  values opaque -> true register residency (budget 238 <= 256 cap);
//  (2) float4 B-loads with matching U layout (elem e = c*256+lane*4+q):
//  4 instead of 16 load insts per node-vector; (3) software pipeline: next
//  node's order/parent issued early, epilogue operands prefetched after bb.
// ---------------------------------------------------------------------------
#define REC_GRID 256
#define GRPSH 4
#define GRP   (1<<GRPSH)            // 16 blocks per barrier-group
#define NGRP  (REC_GRID>>GRPSH)     // 16 groups

__device__ __forceinline__ void gbar(u32* bar){
  __syncthreads();
  if(threadIdx.x==0){
    __threadfence();
    u32* gen  = bar;
    u32* gcnt = bar + 16 + ((blockIdx.x>>GRPSH)<<4);
    u32* root = bar + 16 + (NGRP<<4);
    u32 g = __hip_atomic_load(gen, __ATOMIC_RELAXED, __HIP_MEMORY_SCOPE_AGENT);
    u32 a = __hip_atomic_fetch_add(gcnt, 1u, __ATOMIC_ACQ_REL, __HIP_MEMORY_SCOPE_AGENT);
    if(a == GRP-1u){
      __hip_atomic_store(gcnt, 0u, __ATOMIC_RELAXED, __HIP_MEMORY_SCOPE_AGENT);
      u32 b = __hip_atomic_fetch_add(root, 1u, __ATOMIC_ACQ_REL, __HIP_MEMORY_SCOPE_AGENT);
      if(b == NGRP-1u){
        __hip_atomic_store(root, 0u, __ATOMIC_RELAXED, __HIP_MEMORY_SCOPE_AGENT);
        __hip_atomic_fetch_add(gen, 1u, __ATOMIC_RELEASE, __HIP_MEMORY_SCOPE_AGENT);
      }
    }
    while(__hip_atomic_load(gen, __ATOMIC_ACQUIRE, __HIP_MEMORY_SCOPE_AGENT)==g){
      __builtin_amdgcn_s_sleep(8);
    }
    __threadfence();
  }
  __syncthreads();
}

// combine two accumulator slots a,b across lane stride s.
__device__ __forceinline__ float comb(float a, float b, int s, int lane){
  const bool hi = (lane & s) != 0;
  float send = hi ? a : b;
  float sel  = hi ? b : a;
  return sel + __shfl_xor(send, s, 64);
}

#define PIN4(v) asm volatile("" : "+v"((v).x), "+v"((v).y), "+v"((v).z), "+v"((v).w))

__global__ __launch_bounds__(512,2) void k_rec(
    const int* __restrict__ parent,
    const float* __restrict__ Uz, const float* __restrict__ Ur, const float* __restrict__ Uh,
    float* __restrict__ wz, float* __restrict__ wr, float* __restrict__ wh,
    float* __restrict__ node_h,
    const int* __restrict__ meta, const int* __restrict__ lstart, const int* __restrict__ order,
    u32* __restrict__ bar){
  const int t=threadIdx.x, lane=t&63, wv=t>>6;   // 8 waves
  const int g = blockIdx.x & 7;      // node group (~XCD)
  const int i = blockIdx.x >> 3;     // 0..31 within group
  const bool isZ = i < 16;
  const int rA = ((i&15)<<6) + (wv<<3);  // phase A: 8 rows per wave
  const int rC = (i<<5) + (wv<<2);       // phase C: 4 rows per wave
  const int nlev = meta[0];
  const int l4 = lane<<2;

  // ---- one-time staging (vectorized, layout: elem = c*256 + lane*4 + q) ----
  const float* UA = isZ ? Uz : Ur;
  float4 ua[8][4];
  #pragma unroll
  for(int r=0;r<8;r++)
    #pragma unroll
    for(int c=0;c<4;c++){
      ua[r][c] = *(const float4*)(UA + (size_t)(rA+r)*HID + (c<<8) + l4);
      PIN4(ua[r][c]);
    }
  float4 uh[4][4];
  #pragma unroll
  for(int r=0;r<4;r++)
    #pragma unroll
    for(int c=0;c<4;c++){
      uh[r][c] = *(const float4*)(Uh + (size_t)(rC+r)*HID + (c<<8) + l4);
      PIN4(uh[r][c]);
    }

  for(int lev=0; lev<nlev; ++lev){
    const int s=lstart[lev];
    const int L=lstart[lev+1]-s;
    // ---- phase A: z (i<16) or r (i>=16) rows for this group's nodes ----
    {
      int jj = g;
      int n = (jj<L)? order[s+jj] : 0;
      int p = (jj<L)? parent[n]   : 0;
      while(jj<L){
        const int jn = jj+8;
        int n2=0, p2=0;
        if(jn<L){ n2=order[s+jn]; p2=parent[n2]; }   // issued early (~400cy hidden)
        const float* ph = node_h + (size_t)p*HID;
        float4 bb[4];
        #pragma unroll
        for(int c=0;c<4;c++) bb[c] = *(const float4*)(ph + (c<<8) + l4);
        // epilogue operand prefetch (overlaps FMA chain)
        const int myrow = rA + (lane&7);
        float wv0 = isZ ? wz[(size_t)n*HID + myrow] : wr[(size_t)n*HID + myrow];
        float pv0 = isZ ? 0.f : node_h[(size_t)p*HID + myrow];
        float a0=0.f,a1=0.f,a2=0.f,a3=0.f,a4=0.f,a5=0.f,a6=0.f,a7=0.f;
        #pragma unroll
        for(int c=0;c<4;c++){
          const float4 b=bb[c];
          a0=fmaf(ua[0][c].x,b.x,a0); a0=fmaf(ua[0][c].y,b.y,a0); a0=fmaf(ua[0][c].z,b.z,a0); a0=fmaf(ua[0][c].w,b.w,a0);
          a1=fmaf(ua[1][c].x,b.x,a1); a1=fmaf(ua[1][c].y,b.y,a1); a1=fmaf(ua[1][c].z,b.z,a1); a1=fmaf(ua[1][c].w,b.w,a1);
          a2=fmaf(ua[2][c].x,b.x,a2); a2=fmaf(ua[2][c].y,b.y,a2); a2=fmaf(ua[2][c].z,b.z,a2); a2=fmaf(ua[2][c].w,b.w,a2);
          a3=fmaf(ua[3][c].x,b.x,a3); a3=fmaf(ua[3][c].y,b.y,a3); a3=fmaf(ua[3][c].z,b.z,a3); a3=fmaf(ua[3][c].w,b.w,a3);
          a4=fmaf(ua[4][c].x,b.x,a4); a4=fmaf(ua[4][c].y,b.y,a4); a4=fmaf(ua[4][c].z,b.z,a4); a4=fmaf(ua[4][c].w,b.w,a4);
          a5=fmaf(ua[5][c].x,b.x,a5); a5=fmaf(ua[5][c].y,b.y,a5); a5=fmaf(ua[5][c].z,b.z,a5); a5=fmaf(ua[5][c].w,b.w,a5);
          a6=fmaf(ua[6][c].x,b.x,a6); a6=fmaf(ua[6][c].y,b.y,a6); a6=fmaf(ua[6][c].z,b.z,a6); a6=fmaf(ua[6][c].w,b.w,a6);
          a7=fmaf(ua[7][c].x,b.x,a7); a7=fmaf(ua[7][c].y,b.y,a7); a7=fmaf(ua[7][c].z,b.z,a7); a7=fmaf(ua[7][c].w,b.w,a7);
        }
        float c0=comb(a0,a1,1,lane), c1=comb(a2,a3,1,lane);
        float c2=comb(a4,a5,1,lane), c3=comb(a6,a7,1,lane);
        float d0=comb(c0,c1,2,lane), d1=comb(c2,c3,2,lane);
        float v=comb(d0,d1,4,lane);
        v+=__shfl_xor(v,8,64); v+=__shfl_xor(v,16,64); v+=__shfl_xor(v,32,64);
        if(lane<8){
          const size_t idx=(size_t)n*HID+rA+lane;
          if(isZ) wz[idx]=sigmf(wv0+v);
          else    wr[idx]=sigmf(wv0+v)*pv0;
        }
        jj=jn; n=n2; p=p2;
      }
    }
    gbar(bar);
    // ---- phase C: h-candidate + state update (4 rows per wave) ----
    {
      int jj = g;
      int n = (jj<L)? order[s+jj] : 0;
      int p = (jj<L)? parent[n]   : 0;
      while(jj<L){
        const int jn = jj+8;
        int n2=0, p2=0;
        if(jn<L){ n2=order[s+jn]; p2=parent[n2]; }
        const float* bw = wr + (size_t)n*HID;
        float4 bb[4];
        #pragma unroll
        for(int c=0;c<4;c++) bb[c] = *(const float4*)(bw + (c<<8) + l4);
        const int myrow = rC + (lane&3);
        float zv0 = wz[(size_t)n*HID + myrow];
        float wh0 = wh[(size_t)n*HID + myrow];
        float pv0 = node_h[(size_t)p*HID + myrow];
        float a0=0.f,a1=0.f,a2=0.f,a3=0.f;
        #pragma unroll
        for(int c=0;c<4;c++){
          const float4 b=bb[c];
          a0=fmaf(uh[0][c].x,b.x,a0); a0=fmaf(uh[0][c].y,b.y,a0); a0=fmaf(uh[0][c].z,b.z,a0); a0=fmaf(uh[0][c].w,b.w,a0);
          a1=fmaf(uh[1][c].x,b.x,a1); a1=fmaf(uh[1][c].y,b.y,a1); a1=fmaf(uh[1][c].z,b.z,a1); a1=fmaf(uh[1][c].w,b.w,a1);
          a2=fmaf(uh[2][c].x,b.x,a2); a2=fmaf(uh[2][c].y,b.y,a2); a2=fmaf(uh[2][c].z,b.z,a2); a2=fmaf(uh[2][c].w,b.w,a2);
          a3=fmaf(uh[3][c].x,b.x,a3); a3=fmaf(uh[3][c].y,b.y,a3); a3=fmaf(uh[3][c].z,b.z,a3); a3=fmaf(uh[3][c].w,b.w,a3);
        }
        float c0=comb(a0,a1,1,lane), c1=comb(a2,a3,1,lane);
        float v=comb(c0,c1,2,lane);
        v+=__shfl_xor(v,4,64); v+=__shfl_xor(v,8,64);
        v+=__shfl_xor(v,16,64); v+=__shfl_xor(v,32,64);
        if(lane<4){
          const float c=tanhf(wh0+v);
          node_h[(size_t)(n+1)*HID+rC+lane]=zv0*pv0+(1.f-zv0)*c;
        }
        jj=jn; n=n2; p=p2;
      }
    }
    gbar(bar);
  }
}

// ---------------------------------------------------------------------------
// Leaf max + softmax + loss. Output: FP32 pred[4], loss.
// ---------------------------------------------------------------------------
__global__ __launch_bounds__(1024) void k_final(const float* __restrict__ node_h,
                                                const int* __restrict__ leaf,
                                                const float* __restrict__ Wout,
                                                const float* __restrict__ bout,
                                                const float* __restrict__ y,
                                                float* __restrict__ out){
  __shared__ int li[NLEAVES];
  __shared__ float fs[HID];
  __shared__ float logits[NCLASS];
  const int t=threadIdx.x;
  li[t]=leaf[t];
  __syncthreads();
  float m=-INFINITY;
  for(int l=0;l<NLEAVES;l++) m = fmaxf(m, node_h[(size_t)li[l]*HID + t]);
  fs[t]=m;
  __syncthreads();
  const int wave=t>>6, lane=t&63;
  if(wave<NCLASS){
    float p=0.f;
    for(int h=lane;h<HID;h+=64) p += Wout[wave*HID+h]*fs[h];
    for(int off=32; off; off>>=1) p += __shfl_down(p, off);
    if(lane==0) logits[wave]=p+bout[wave];
  }
  __syncthreads();
  if(t==0){
    float mx = fmaxf(fmaxf(logits[0],logits[1]),fmaxf(logits[2],logits[3]));
    float ev[NCLASS]; float es=0.f;
    #pragma unroll
    for(int c=0;c<NCLASS;c++){ ev[c]=expf(logits[c]-mx); es+=ev[c]; }
    float loss=0.f;
    #pragma unroll
    for(int c=0;c<NCLASS;c++){
      float p=ev[c]/es;
      out[c]=p;
      float d=y[c]-p; loss+=d*d;
    }
    out[NCLASS]=loss;
  }
}

// ---------------------------------------------------------------------------
extern "C" void kernel_launch(void* const* d_in, const int* in_sizes, int n_in,
                              void* d_out, int out_size, void* d_ws, size_t ws_size,
                              hipStream_t stream){
  (void)in_sizes; (void)n_in; (void)out_size;
  const float* x_word=(const float*)d_in[0];
  const int*   x_index=(const int*)d_in[1];
  const int*   parent =(const int*)d_in[2];
  const int*   leaf   =(const int*)d_in[3];
  const float* y      =(const float*)d_in[4];
  const float* E      =(const float*)d_in[5];
  const float* W_z=(const float*)d_in[6];  const float* U_z=(const float*)d_in[7];  const float* b_z=(const float*)d_in[8];
  const float* W_r=(const float*)d_in[9];  const float* U_r=(const float*)d_in[10]; const float* b_r=(const float*)d_in[11];
  const float* W_h=(const float*)d_in[12]; const float* U_h=(const float*)d_in[13]; const float* b_h=(const float*)d_in[14];
  const float* W_out=(const float*)d_in[15]; const float* b_out=(const float*)d_in[16];

  size_t off=0;
  char* wsb=(char*)d_ws;
  auto alloc=[&](size_t b)->void*{ void* p=wsb+off; off=(off+b+255)&~(size_t)255; return p; };
  u32*  bar    = (u32*)  alloc(4096);
  int*  meta   = (int*)  alloc(256);
  int*  lstart = (int*)  alloc((N_NODES+1)*sizeof(int));
  int*  order  = (int*)  alloc(N_NODES*sizeof(int));
  float* node_h= (float*)alloc((size_t)(N_NODES+1)*HID*sizeof(float));
  float* xe    = (float*)alloc((size_t)N_NODES*HID*sizeof(float));
  float* wz    = (float*)alloc((size_t)N_NODES*HID*sizeof(float));
  float* wr    = (float*)alloc((size_t)N_NODES*HID*sizeof(float));
  float* wh    = (float*)alloc((size_t)N_NODES*HID*sizeof(float));
  float* ET    = (float*)(wsb+off);
  const size_t need_ET = off + (size_t)VOCAB*HID*sizeof(float);
  const bool useET = (ws_size >= need_ET);

  hipMemsetAsync(bar, 0, 4096, stream);
  k_levels<<<1,1024,0,stream>>>(parent, meta, lstart, order, node_h);
  if(useET){
    k_transpose<<<dim3((VOCAB+31)/32, HID/32),256,0,stream>>>(E, ET);
    k_xe<<<N_NODES,256,0,stream>>>(ET, x_word, x_index, xe);
  }else{
    k_xe_noET<<<N_NODES,256,0,stream>>>(E, x_word, x_index, xe);
  }
  k_gemm_in<<<dim3(N_NODES/64, HID/64, 3),256,0,stream>>>(xe, W_z,W_r,W_h, b_z,b_r,b_h, wz,wr,wh);
  k_rec<<<REC_GRID,512,0,stream>>>(parent, U_z,U_r,U_h, wz,wr,wh, node_h, meta, lstart, order, bar);
  k_final<<<1,1024,0,stream>>>(node_h, leaf, W_out, b_out, y, (float*)d_out);
}

// Round 10
// 2500.490 us; speedup vs baseline: 2.3679x; 1.0267x over previous
//
#include <hip/hip_runtime.h>
#include <hip/hip_bf16.h>
#include <math.h>

#define N_NODES 4096
#define WPN 32
#define HID 1024
#define VOCAB 30000
#define NCLASS 4
#define NLEAVES 1024

typedef unsigned int u32;
typedef unsigned short u16;

__device__ __forceinline__ float sigmf(float x){ return 1.f/(1.f+expf(-x)); }

// ---------------------------------------------------------------------------
// Level schedule: depth[i] via iterative relaxation in LDS, then counting sort.
// Also zeroes node_h row 0 (root parent).
// ---------------------------------------------------------------------------
__global__ __launch_bounds__(1024) void k_levels(const int* __restrict__ parent,
                                                 int* __restrict__ meta,
                                                 int* __restrict__ lstart,
                                                 int* __restrict__ order,
                                                 float* __restrict__ node_h){
  __shared__ int dep[N_NODES];
  __shared__ int dpt[N_NODES];
  __shared__ int cnt[N_NODES];
  __shared__ int changed, maxd;
  const int t = threadIdx.x;
  for(int i=t;i<N_NODES;i+=1024){ dep[i]=parent[i]-1; dpt[i]=0; cnt[i]=0; }
  if(t==0){ maxd=0; }
  node_h[t]=0.f;  // 1024 threads == HID: zero root-parent row
  __syncthreads();
  while(true){
    if(t==0) changed=0;
    __syncthreads();
    bool ch=false;
    for(int i=t;i<N_NODES;i+=1024){
      int d = (dep[i]<0)? 0 : (dpt[dep[i]]+1);
      if(d>dpt[i]){ dpt[i]=d; ch=true; }
    }
    if(ch) changed=1;
    __syncthreads();
    if(!changed) break;
    __syncthreads();
  }
  __syncthreads();
  for(int i=t;i<N_NODES;i+=1024){ atomicAdd(&cnt[dpt[i]],1); atomicMax(&maxd,dpt[i]); }
  __syncthreads();
  // inclusive scan of cnt -> sc (reuse dep)
  int* sc = dep;
  for(int i=t;i<N_NODES;i+=1024) sc[i]=cnt[i];
  __syncthreads();
  for(int off=1; off<N_NODES; off<<=1){
    int v[4];
    #pragma unroll
    for(int u=0;u<4;u++){ int i=t+u*1024; v[u] = (i>=off)? sc[i-off] : 0; }
    __syncthreads();
    #pragma unroll
    for(int u=0;u<4;u++){ int i=t+u*1024; sc[i]+=v[u]; }
    __syncthreads();
  }
  for(int i=t;i<N_NODES;i+=1024) lstart[i+1]=sc[i];
  if(t==0){ lstart[0]=0; meta[0]=maxd+1; }
  // exclusive starts into cnt for scatter
  for(int i=t;i<N_NODES;i+=1024) cnt[i]=sc[i]-cnt[i];
  __syncthreads();
  for(int i=t;i<N_NODES;i+=1024){
    int pos = atomicAdd(&cnt[dpt[i]],1);
    order[pos]=i;
  }
}

// ---------------------------------------------------------------------------
// E [HID][VOCAB] f32  ->  ET [VOCAB][HID] f32  (tiled transpose)
// ---------------------------------------------------------------------------
__global__ __launch_bounds__(256) void k_transpose(const float* __restrict__ E,
                                                   float* __restrict__ ET){
  __shared__ float tile[32][33];
  const int v0 = blockIdx.x*32, h0 = blockIdx.y*32;
  const int tx = threadIdx.x%32, ty = threadIdx.x/32;   // ty 0..7
  #pragma unroll
  for(int i=0;i<4;i++){
    int h = h0+ty+8*i, v = v0+tx;
    tile[ty+8*i][tx] = (v<VOCAB)? E[(size_t)h*VOCAB + v] : 0.f;
  }
  __syncthreads();
  #pragma unroll
  for(int i=0;i<4;i++){
    int v = v0+ty+8*i, h = h0+tx;
    if(v<VOCAB) ET[(size_t)v*HID + h] = tile[tx][ty+8*i];
  }
}

// ---------------------------------------------------------------------------
// xe[n,h] = sum_l w[n,l] * ET[idx[n,l], h]   (one block per node, coalesced)
// ---------------------------------------------------------------------------
__global__ __launch_bounds__(256) void k_xe(const float* __restrict__ ET,
                                            const float* __restrict__ xw,
                                            const int* __restrict__ xi,
                                            float* __restrict__ xe){
  const int n = blockIdx.x;
  __shared__ float w[WPN]; __shared__ int id[WPN];
  const int t = threadIdx.x;
  if(t<WPN){ w[t]=xw[n*WPN+t]; id[t]=xi[n*WPN+t]; }
  __syncthreads();
  const int h0 = t*4;
  float a0=0,a1=0,a2=0,a3=0;
  for(int l=0;l<WPN;l++){
    const float4 e = *(const float4*)(ET + (size_t)id[l]*HID + h0);
    const float wl = w[l];
    a0 += wl*e.x; a1 += wl*e.y; a2 += wl*e.z; a3 += wl*e.w;
  }
  *(float4*)(xe + (size_t)n*HID + h0) = make_float4(a0,a1,a2,a3);
}

// Fallback when ws too small for fp32 ET: direct strided gather from E.
__global__ __launch_bounds__(256) void k_xe_noET(const float* __restrict__ E,
                                                 const float* __restrict__ xw,
                                                 const int* __restrict__ xi,
                                                 float* __restrict__ xe){
  const int n = blockIdx.x;
  __shared__ float w[WPN]; __shared__ int id[WPN];
  const int t = threadIdx.x;
  if(t<WPN){ w[t]=xw[n*WPN+t]; id[t]=xi[n*WPN+t]; }
  __syncthreads();
  const int h0 = t*4;
  float acc[4]={0,0,0,0};
  for(int l=0;l<WPN;l++){
    const float wl=w[l]; const int ix=id[l];
    #pragma unroll
    for(int j=0;j<4;j++) acc[j] += wl*E[(size_t)(h0+j)*VOCAB + ix];
  }
  *(float4*)(xe + (size_t)n*HID + h0) = make_float4(acc[0],acc[1],acc[2],acc[3]);
}

// ---------------------------------------------------------------------------
// Input-side projections: out_g[n,o] = b_g[o] + sum_k xe[n,k]*W_g[o,k]
// 64x64 tile, BK=32, k-major LDS, 4x4 micro-tile.
// ---------------------------------------------------------------------------
__global__ __launch_bounds__(256) void k_gemm_in(const float* __restrict__ xe,
  const float* __restrict__ W0,const float* __restrict__ W1,const float* __restrict__ W2,
  const float* __restrict__ b0,const float* __restrict__ b1,const float* __restrict__ b2,
  float* __restrict__ o0p,float* __restrict__ o1p,float* __restrict__ o2p){
  __shared__ float A[32*68];
  __shared__ float B[32*68];
  const int g=blockIdx.z;
  const float* W  = (g==0)?W0:((g==1)?W1:W2);
  const float* bi = (g==0)?b0:((g==1)?b1:b2);
  float* out      = (g==0)?o0p:((g==1)?o1p:o2p);
  const int n0=blockIdx.x<<6, q0=blockIdx.y<<6;
  const int t=threadIdx.x, tx=t&15, ty=t>>4;
  float acc[4][4]={};
  for(int k0=0;k0<HID;k0+=32){
    #pragma unroll
    for(int m=0;m<2;m++){
      int idx=t+(m<<8); int r=idx>>3; int c4=(idx&7)<<2;
      float4 v=*(const float4*)(xe+(size_t)(n0+r)*HID+k0+c4);
      A[(c4+0)*68+r]=v.x; A[(c4+1)*68+r]=v.y; A[(c4+2)*68+r]=v.z; A[(c4+3)*68+r]=v.w;
      float4 u=*(const float4*)(W+(size_t)(q0+r)*HID+k0+c4);
      B[(c4+0)*68+r]=u.x; B[(c4+1)*68+r]=u.y; B[(c4+2)*68+r]=u.z; B[(c4+3)*68+r]=u.w;
    }
    __syncthreads();
    #pragma unroll 8
    for(int k=0;k<32;k++){
      const float4 a=*(const float4*)&A[k*68+(ty<<2)];
      const float4 b=*(const float4*)&B[k*68+(tx<<2)];
      acc[0][0]+=a.x*b.x; acc[0][1]+=a.x*b.y; acc[0][2]+=a.x*b.z; acc[0][3]+=a.x*b.w;
      acc[1][0]+=a.y*b.x; acc[1][1]+=a.y*b.y; acc[1][2]+=a.y*b.z; acc[1][3]+=a.y*b.w;
      acc[2][0]+=a.z*b.x; acc[2][1]+=a.z*b.y; acc[2][2]+=a.z*b.z; acc[2][3]+=a.z*b.w;
      acc[3][0]+=a.w*b.x; acc[3][1]+=a.w*b.y; acc[3][2]+=a.w*b.z; acc[3][3]+=a.w*b.w;
    }
    __syncthreads();
  }
  const float4 bb=*(const float4*)(bi+q0+(tx<<2));
  #pragma unroll
  for(int i=0;i<4;i++){
    const int n=n0+(ty<<2)+i;
    float4 r4 = make_float4(acc[i][0]+bb.x, acc[i][1]+bb.y, acc[i][2]+bb.z, acc[i][3]+bb.w);
    *(float4*)(out+(size_t)n*HID+q0+(tx<<2)) = r4;
  }
}

// ---------------------------------------------------------------------------
// Persistent level-synchronous recurrence, v8 "fit the allocator":
//  Round-9 evidence: VGPR_Count=124 < 192 floats/lane demanded => allocator
//  SPILLED the pinned U to scratch (scratch reload == L2 reload == flat perf).
//  v8 strategy: shrink the live payload under the compiler's ~128-VGPR
//  comfort zone instead of fighting it:
//   - Uh (tanh path, precision-critical): 32 rows/block in 128KB LDS, fp32,
//     staged once. Conflict-free ds_read_b128 streams.
//   - Uz/Ur (gate path, sigmoid * 0.25 Lipschitz): 64 rows/block as
//     bf16-PACKED u32 registers: 64 VGPRs payload (was 128 fp32), pinned.
//     Math stays fp32 (unpack = shift/and).
//   - A->C barrier is now GROUP-LOCAL (32 blocks, one XCD); only the level
//     boundary uses the global tree barrier: 50 global -> 25 global+25 local.
// ---------------------------------------------------------------------------
#define REC_GRID 256
#define GRPSH 4
#define GRP   (1<<GRPSH)            // 16 blocks per barrier-group
#define NGRP  (REC_GRID>>GRPSH)     // 16 groups

__device__ __forceinline__ void gbar(u32* bar){
  __syncthreads();
  if(threadIdx.x==0){
    __threadfence();
    u32* gen  = bar;
    u32* gcnt = bar + 16 + ((blockIdx.x>>GRPSH)<<4);
    u32* root = bar + 16 + (NGRP<<4);
    u32 g = __hip_atomic_load(gen, __ATOMIC_RELAXED, __HIP_MEMORY_SCOPE_AGENT);
    u32 a = __hip_atomic_fetch_add(gcnt, 1u, __ATOMIC_ACQ_REL, __HIP_MEMORY_SCOPE_AGENT);
    if(a == GRP-1u){
      __hip_atomic_store(gcnt, 0u, __ATOMIC_RELAXED, __HIP_MEMORY_SCOPE_AGENT);
      u32 b = __hip_atomic_fetch_add(root, 1u, __ATOMIC_ACQ_REL, __HIP_MEMORY_SCOPE_AGENT);
      if(b == NGRP-1u){
        __hip_atomic_store(root, 0u, __ATOMIC_RELAXED, __HIP_MEMORY_SCOPE_AGENT);
        __hip_atomic_fetch_add(gen, 1u, __ATOMIC_RELEASE, __HIP_MEMORY_SCOPE_AGENT);
      }
    }
    while(__hip_atomic_load(gen, __ATOMIC_ACQUIRE, __HIP_MEMORY_SCOPE_AGENT)==g){
      __builtin_amdgcn_s_sleep(8);
    }
    __threadfence();
  }
  __syncthreads();
}

// group-local barrier: the 32 blocks with blockIdx&7==xg (all on one XCD).
__device__ __forceinline__ void gbar_grp(u32* bar, int xg){
  __syncthreads();
  if(threadIdx.x==0){
    __threadfence();
    u32* gcnt = bar + 512 + (xg<<4);
    u32* ggen = bar + 512 + (xg<<4) + 8;
    u32 g = __hip_atomic_load(ggen, __ATOMIC_RELAXED, __HIP_MEMORY_SCOPE_AGENT);
    u32 a = __hip_atomic_fetch_add(gcnt, 1u, __ATOMIC_ACQ_REL, __HIP_MEMORY_SCOPE_AGENT);
    if(a == 31u){
      __hip_atomic_store(gcnt, 0u, __ATOMIC_RELAXED, __HIP_MEMORY_SCOPE_AGENT);
      __hip_atomic_fetch_add(ggen, 1u, __ATOMIC_RELEASE, __HIP_MEMORY_SCOPE_AGENT);
    }else{
      while(__hip_atomic_load(ggen, __ATOMIC_ACQUIRE, __HIP_MEMORY_SCOPE_AGENT)==g){
        __builtin_amdgcn_s_sleep(4);
      }
    }
    __threadfence();
  }
  __syncthreads();
}

// combine two accumulator slots a,b across lane stride s.
__device__ __forceinline__ float comb(float a, float b, int s, int lane){
  const bool hi = (lane & s) != 0;
  float send = hi ? a : b;
  float sel  = hi ? b : a;
  return sel + __shfl_xor(send, s, 64);
}

__device__ __forceinline__ u32 packbf(float lo, float hi){
  u32 x=__float_as_uint(lo), y=__float_as_uint(hi);
  x = (x + 0x7fffu + ((x>>16)&1u)) >> 16;
  y = (y + 0x7fffu + ((y>>16)&1u)) & 0xffff0000u;
  return y | x;
}
__device__ __forceinline__ float bf_lo(u32 u){ return __uint_as_float(u<<16); }
__device__ __forceinline__ float bf_hi(u32 u){ return __uint_as_float(u & 0xffff0000u); }

#define PIN1(v) asm volatile("" : "+v"(v))

__global__ __launch_bounds__(512,2) void k_rec(
    const int* __restrict__ parent,
    const float* __restrict__ Uz, const float* __restrict__ Ur, const float* __restrict__ Uh,
    float* __restrict__ wz, float* __restrict__ wr, float* __restrict__ wh,
    float* __restrict__ node_h,
    const int* __restrict__ meta, const int* __restrict__ lstart, const int* __restrict__ order,
    u32* __restrict__ bar){
  __shared__ float UhL[32*HID];      // 128 KB: this block's 32 rows of U_h
  const int t=threadIdx.x, lane=t&63, wv=t>>6;   // 8 waves
  const int xg = blockIdx.x & 7;     // node group == XCD (blocks b%8==xg land on XCD xg)
  const int i  = blockIdx.x >> 3;    // 0..31 within group
  const bool isZ = i < 16;
  const int rA  = ((i&15)<<6) + (wv<<3);  // phase A: 8 rows per wave
  const int rC0 = i<<5;                   // phase C: block's 32 rows
  const int nlev = meta[0];
  const int l4 = lane<<2;

  // ---- one-time staging ----
  // Uz/Ur rows -> bf16-packed registers (64 u32/lane), pinned.
  const float* UA = isZ ? Uz : Ur;
  u32 uap[8][8];
  #pragma unroll
  for(int r=0;r<8;r++)
    #pragma unroll
    for(int c=0;c<4;c++){
      const float4 v = *(const float4*)(UA + (size_t)(rA+r)*HID + (c<<8) + l4);
      uap[r][c*2]   = packbf(v.x, v.y);
      uap[r][c*2+1] = packbf(v.z, v.w);
      PIN1(uap[r][c*2]); PIN1(uap[r][c*2+1]);
    }
  // Uh rows -> LDS (fp32 exact).
  for(int x=t; x<32*HID; x+=512) UhL[x] = Uh[(size_t)rC0*HID + x];
  __syncthreads();

  for(int lev=0; lev<nlev; ++lev){
    const int s=lstart[lev];
    const int L=lstart[lev+1]-s;
    // ---- phase A: z (i<16) or r (i>=16) rows for this group's nodes ----
    {
      int jj = xg;
      int n = (jj<L)? order[s+jj] : 0;
      int p = (jj<L)? parent[n]   : 0;
      while(jj<L){
        const int jn = jj+8;
        int n2=0, p2=0;
        if(jn<L){ n2=order[s+jn]; p2=parent[n2]; }   // next-node meta, issued early
        const float* ph = node_h + (size_t)p*HID;
        float4 bb[4];
        #pragma unroll
        for(int c=0;c<4;c++) bb[c] = *(const float4*)(ph + (c<<8) + l4);
        const int myrow = rA + (lane&7);
        float wv0 = isZ ? wz[(size_t)n*HID + myrow] : wr[(size_t)n*HID + myrow];
        float pv0 = isZ ? 0.f : node_h[(size_t)p*HID + myrow];
        float a0=0.f,a1=0.f,a2=0.f,a3=0.f,a4=0.f,a5=0.f,a6=0.f,a7=0.f;
        #pragma unroll
        for(int c=0;c<4;c++){
          const float4 b=bb[c];
          #define ROWFMA(acc,r) { const u32 p0=uap[r][c*2], p1=uap[r][c*2+1]; \
            acc=fmaf(bf_lo(p0),b.x,acc); acc=fmaf(bf_hi(p0),b.y,acc); \
            acc=fmaf(bf_lo(p1),b.z,acc); acc=fmaf(bf_hi(p1),b.w,acc); }
          ROWFMA(a0,0) ROWFMA(a1,1) ROWFMA(a2,2) ROWFMA(a3,3)
          ROWFMA(a4,4) ROWFMA(a5,5) ROWFMA(a6,6) ROWFMA(a7,7)
          #undef ROWFMA
        }
        float c0=comb(a0,a1,1,lane), c1=comb(a2,a3,1,lane);
        float c2=comb(a4,a5,1,lane), c3=comb(a6,a7,1,lane);
        float d0=comb(c0,c1,2,lane), d1=comb(c2,c3,2,lane);
        float v=comb(d0,d1,4,lane);
        v+=__shfl_xor(v,8,64); v+=__shfl_xor(v,16,64); v+=__shfl_xor(v,32,64);
        if(lane<8){
          const size_t idx=(size_t)n*HID+rA+lane;
          if(isZ) wz[idx]=sigmf(wv0+v);
          else    wr[idx]=sigmf(wv0+v)*pv0;
        }
        jj=jn; n=n2; p=p2;
      }
    }
    gbar_grp(bar, xg);   // r/z producers and consumers are all in this group
    // ---- phase C: h-candidate + state update (4 rows per wave, Uh in LDS) ----
    {
      int jj = xg;
      int n = (jj<L)? order[s+jj] : 0;
      int p = (jj<L)? parent[n]   : 0;
      while(jj<L){
        const int jn = jj+8;
        int n2=0, p2=0;
        if(jn<L){ n2=order[s+jn]; p2=parent[n2]; }
        const float* bw = wr + (size_t)n*HID;
        float4 bb[4];
        #pragma unroll
        for(int c=0;c<4;c++) bb[c] = *(const float4*)(bw + (c<<8) + l4);
        const int myrow = rC0 + (wv<<2) + (lane&3);
        float zv0 = wz[(size_t)n*HID + myrow];
        float wh0 = wh[(size_t)n*HID + myrow];
        float pv0 = node_h[(size_t)p*HID + myrow];
        float a0=0.f,a1=0.f,a2=0.f,a3=0.f;
        #pragma unroll
        for(int c=0;c<4;c++){
          const float4 b=bb[c];
          const float4 u0 = *(const float4*)&UhL[((wv<<2)+0)*HID + (c<<8) + l4];
          const float4 u1 = *(const float4*)&UhL[((wv<<2)+1)*HID + (c<<8) + l4];
          const float4 u2 = *(const float4*)&UhL[((wv<<2)+2)*HID + (c<<8) + l4];
          const float4 u3 = *(const float4*)&UhL[((wv<<2)+3)*HID + (c<<8) + l4];
          a0=fmaf(u0.x,b.x,a0); a0=fmaf(u0.y,b.y,a0); a0=fmaf(u0.z,b.z,a0); a0=fmaf(u0.w,b.w,a0);
          a1=fmaf(u1.x,b.x,a1); a1=fmaf(u1.y,b.y,a1); a1=fmaf(u1.z,b.z,a1); a1=fmaf(u1.w,b.w,a1);
          a2=fmaf(u2.x,b.x,a2); a2=fmaf(u2.y,b.y,a2); a2=fmaf(u2.z,b.z,a2); a2=fmaf(u2.w,b.w,a2);
          a3=fmaf(u3.x,b.x,a3); a3=fmaf(u3.y,b.y,a3); a3=fmaf(u3.z,b.z,a3); a3=fmaf(u3.w,b.w,a3);
        }
        float c0=comb(a0,a1,1,lane), c1=comb(a2,a3,1,lane);
        float v=comb(c0,c1,2,lane);
        v+=__shfl_xor(v,4,64); v+=__shfl_xor(v,8,64);
        v+=__shfl_xor(v,16,64); v+=__shfl_xor(v,32,64);
        if(lane<4){
          const float c=tanhf(wh0+v);
          node_h[(size_t)(n+1)*HID+myrow]=zv0*pv0+(1.f-zv0)*c;
        }
        jj=jn; n=n2; p=p2;
      }
    }
    gbar(bar);   // level boundary: parents cross groups -> global
  }
}

// ---------------------------------------------------------------------------
// Leaf max + softmax + loss. Output: FP32 pred[4], loss.
// ---------------------------------------------------------------------------
__global__ __launch_bounds__(1024) void k_final(const float* __restrict__ node_h,
                                                const int* __restrict__ leaf,
                                                const float* __restrict__ Wout,
                                                const float* __restrict__ bout,
                                                const float* __restrict__ y,
                                                float* __restrict__ out){
  __shared__ int li[NLEAVES];
  __shared__ float fs[HID];
  __shared__ float logits[NCLASS];
  const int t=threadIdx.x;
  li[t]=leaf[t];
  __syncthreads();
  float m=-INFINITY;
  for(int l=0;l<NLEAVES;l++) m = fmaxf(m, node_h[(size_t)li[l]*HID + t]);
  fs[t]=m;
  __syncthreads();
  const int wave=t>>6, lane=t&63;
  if(wave<NCLASS){
    float p=0.f;
    for(int h=lane;h<HID;h+=64) p += Wout[wave*HID+h]*fs[h];
    for(int off=32; off; off>>=1) p += __shfl_down(p, off);
    if(lane==0) logits[wave]=p+bout[wave];
  }
  __syncthreads();
  if(t==0){
    float mx = fmaxf(fmaxf(logits[0],logits[1]),fmaxf(logits[2],logits[3]));
    float ev[NCLASS]; float es=0.f;
    #pragma unroll
    for(int c=0;c<NCLASS;c++){ ev[c]=expf(logits[c]-mx); es+=ev[c]; }
    float loss=0.f;
    #pragma unroll
    for(int c=0;c<NCLASS;c++){
      float p=ev[c]/es;
      out[c]=p;
      float d=y[c]-p; loss+=d*d;
    }
    out[NCLASS]=loss;
  }
}

// ---------------------------------------------------------------------------
extern "C" void kernel_launch(void* const* d_in, const int* in_sizes, int n_in,
                              void* d_out, int out_size, void* d_ws, size_t ws_size,
                              hipStream_t stream){
  (void)in_sizes; (void)n_in; (void)out_size;
  const float* x_word=(const float*)d_in[0];
  const int*   x_index=(const int*)d_in[1];
  const int*   parent =(const int*)d_in[2];
  const int*   leaf   =(const int*)d_in[3];
  const float* y      =(const float*)d_in[4];
  const float* E      =(const float*)d_in[5];
  const float* W_z=(const float*)d_in[6];  const float* U_z=(const float*)d_in[7];  const float* b_z=(const float*)d_in[8];
  const float* W_r=(const float*)d_in[9];  const float* U_r=(const float*)d_in[10]; const float* b_r=(const float*)d_in[11];
  const float* W_h=(const float*)d_in[12]; const float* U_h=(const float*)d_in[13]; const float* b_h=(const float*)d_in[14];
  const float* W_out=(const float*)d_in[15]; const float* b_out=(const float*)d_in[16];

  size_t off=0;
  char* wsb=(char*)d_ws;
  auto alloc=[&](size_t b)->void*{ void* p=wsb+off; off=(off+b+255)&~(size_t)255; return p; };
  u32*  bar    = (u32*)  alloc(4096);
  int*  meta   = (int*)  alloc(256);
  int*  lstart = (int*)  alloc((N_NODES+1)*sizeof(int));
  int*  order  = (int*)  alloc(N_NODES*sizeof(int));
  float* node_h= (float*)alloc((size_t)(N_NODES+1)*HID*sizeof(float));
  float* xe    = (float*)alloc((size_t)N_NODES*HID*sizeof(float));
  float* wz    = (float*)alloc((size_t)N_NODES*HID*sizeof(float));
  float* wr    = (float*)alloc((size_t)N_NODES*HID*sizeof(float));
  float* wh    = (float*)alloc((size_t)N_NODES*HID*sizeof(float));
  float* ET    = (float*)(wsb+off);
  const size_t need_ET = off + (size_t)VOCAB*HID*sizeof(float);
  const bool useET = (ws_size >= need_ET);

  hipMemsetAsync(bar, 0, 4096, stream);
  k_levels<<<1,1024,0,stream>>>(parent, meta, lstart, order, node_h);
  if(useET){
    k_transpose<<<dim3((VOCAB+31)/32, HID/32),256,0,stream>>>(E, ET);
    k_xe<<<N_NODES,256,0,stream>>>(ET, x_word, x_index, xe);
  }else{
    k_xe_noET<<<N_NODES,256,0,stream>>>(E, x_word, x_index, xe);
  }
  k_gemm_in<<<dim3(N_NODES/64, HID/64, 3),256,0,stream>>>(xe, W_z,W_r,W_h, b_z,b_r,b_h, wz,wr,wh);
  k_rec<<<REC_GRID,512,0,stream>>>(parent, U_z,U_r,U_h, wz,wr,wh, node_h, meta, lstart, order, bar);
  k_final<<<1,1024,0,stream>>>(node_h, leaf, W_out, b_out, y, (float*)d_out);
}